// Round 1
// 1290.472 us; speedup vs baseline: 1.0046x; 1.0046x over previous
//
#include <hip/hip_runtime.h>
#include <hip/hip_bf16.h>
#include <math.h>

#define S_LEN 4096
#define HID   2048
#define NH    8
#define NVH   16
#define DK    128
#define DV    128
#define KEY_DIM  (NH*DK)    // 1024
#define VAL_DIM  (NVH*DV)   // 2048
#define SCALE_Q  0.08838834764831845f  // 128^-0.5
#define CCH 64              // chunk length
#define NCH (S_LEN/CCH)     // 64 chunks

typedef __attribute__((ext_vector_type(8))) short short8;   // 8 bf16
typedef __attribute__((ext_vector_type(4))) float f32x4;

// ---------------------------------------------------------------------------
// float -> bf16 cast
// ---------------------------------------------------------------------------
__global__ __launch_bounds__(256) void cast_f2b(
    const float* __restrict__ in, __hip_bfloat16* __restrict__ out, int n) {
  int i = (blockIdx.x * 256 + threadIdx.x) * 4;
  if (i >= n) return;
  float4 v = *(const float4*)&in[i];
  union { __hip_bfloat16 b[4]; short4 s; } u;
  u.b[0] = __float2bfloat16(v.x); u.b[1] = __float2bfloat16(v.y);
  u.b[2] = __float2bfloat16(v.z); u.b[3] = __float2bfloat16(v.w);
  *(short4*)&out[i] = u.s;
}

// ---------------------------------------------------------------------------
// bf16 MFMA GEMM: C[M,N](fp32) = A[M,K] @ B[N,K]^T  (m97 structure)
// ---------------------------------------------------------------------------
__device__ __forceinline__ void lds_load16(const __hip_bfloat16* g,
                                           __hip_bfloat16* l) {
  __builtin_amdgcn_global_load_lds(
      (const __attribute__((address_space(1))) unsigned int*)g,
      (__attribute__((address_space(3))) unsigned int*)l, 16, 0, 0);
}

__global__ __launch_bounds__(256) void gemm_bf16_bt(
    const __hip_bfloat16* __restrict__ A, const __hip_bfloat16* __restrict__ B,
    float* __restrict__ C, int M, int N, int K) {
  __shared__ __hip_bfloat16 sA[128 * 32];
  __shared__ __hip_bfloat16 sB[128 * 32];
  const int t = threadIdx.x;
  const int wave = t >> 6, lane = t & 63;
  const int bm = blockIdx.y, bn = blockIdx.x;
  const int wm = (wave & 1) * 64, wn = (wave >> 1) * 64;

  f32x4 zero = {0.f, 0.f, 0.f, 0.f};
  f32x4 acc[4][4];
  #pragma unroll
  for (int i = 0; i < 4; i++)
    #pragma unroll
    for (int j = 0; j < 4; j++) acc[i][j] = zero;

  const int r0 = t >> 2,        c0 = (t & 3) * 8;
  const int r1 = (256 + t) >> 2, c1 = ((256 + t) & 3) * 8;
  const __hip_bfloat16* gA0 = A + (size_t)(bm * 128 + r0) * K + c0;
  const __hip_bfloat16* gA1 = A + (size_t)(bm * 128 + r1) * K + c1;
  const __hip_bfloat16* gB0 = B + (size_t)(bn * 128 + r0) * K + c0;
  const __hip_bfloat16* gB1 = B + (size_t)(bn * 128 + r1) * K + c1;
  __hip_bfloat16* lA0 = sA + (size_t)(wave * 64) * 8;
  __hip_bfloat16* lA1 = sA + (size_t)(256 + wave * 64) * 8;
  __hip_bfloat16* lB0 = sB + (size_t)(wave * 64) * 8;
  __hip_bfloat16* lB1 = sB + (size_t)(256 + wave * 64) * 8;

  const int fm = lane & 15, fk = (lane >> 4) * 8;

  for (int k0 = 0; k0 < K; k0 += 32) {
    lds_load16(gA0, lA0); lds_load16(gA1, lA1);
    lds_load16(gB0, lB0); lds_load16(gB1, lB1);
    gA0 += 32; gA1 += 32; gB0 += 32; gB1 += 32;
    __syncthreads();
    short8 a[4], b[4];
    #pragma unroll
    for (int i = 0; i < 4; i++)
      a[i] = *(const short8*)&sA[(size_t)(wm + i * 16 + fm) * 32 + fk];
    #pragma unroll
    for (int j = 0; j < 4; j++)
      b[j] = *(const short8*)&sB[(size_t)(wn + j * 16 + fm) * 32 + fk];
    #pragma unroll
    for (int i = 0; i < 4; i++)
      #pragma unroll
      for (int j = 0; j < 4; j++)
        acc[i][j] = __builtin_amdgcn_mfma_f32_16x16x32_bf16(a[i], b[j], acc[i][j], 0, 0, 0);
    __syncthreads();
  }
  #pragma unroll
  for (int i = 0; i < 4; i++) {
    #pragma unroll
    for (int j = 0; j < 4; j++) {
      int col = bn * 128 + wn + j * 16 + (lane & 15);
      int rw0 = bm * 128 + wm + i * 16 + (lane >> 4) * 4;
      #pragma unroll
      for (int r = 0; r < 4; r++)
        C[(size_t)(rw0 + r) * N + col] = acc[i][j][r];
    }
  }
}

// ---------------------------------------------------------------------------
// fp32 GEMM for the tiny N=16 projections (Wa, Wb)
// ---------------------------------------------------------------------------
__global__ __launch_bounds__(256) void gemm_bt(
    const float* __restrict__ A, const float* __restrict__ B,
    float* __restrict__ C, int M, int N, int K) {
  __shared__ float As[16][68];
  __shared__ float Bs[16][68];
  const int bm = blockIdx.y, bn = blockIdx.x;
  const int t = threadIdx.x;
  const int tx = t & 15, ty = t >> 4;
  const int lrow = t >> 2;
  const int lk0  = (t & 3) * 4;
  const int arow = bm * 64 + lrow;
  const int brow = bn * 64 + lrow;
  const bool bvalid = brow < N;

  float acc[4][4];
  #pragma unroll
  for (int i = 0; i < 4; i++)
    #pragma unroll
    for (int j = 0; j < 4; j++) acc[i][j] = 0.f;

  for (int k0 = 0; k0 < K; k0 += 16) {
    float4 av = *(const float4*)&A[(size_t)arow * K + k0 + lk0];
    float4 bv = bvalid ? *(const float4*)&B[(size_t)brow * K + k0 + lk0]
                       : make_float4(0.f, 0.f, 0.f, 0.f);
    As[lk0+0][lrow] = av.x; As[lk0+1][lrow] = av.y;
    As[lk0+2][lrow] = av.z; As[lk0+3][lrow] = av.w;
    Bs[lk0+0][lrow] = bv.x; Bs[lk0+1][lrow] = bv.y;
    Bs[lk0+2][lrow] = bv.z; Bs[lk0+3][lrow] = bv.w;
    __syncthreads();
    #pragma unroll
    for (int kk = 0; kk < 16; kk++) {
      float4 a = *(const float4*)&As[kk][ty * 4];
      float4 b = *(const float4*)&Bs[kk][tx * 4];
      float ar[4] = {a.x, a.y, a.z, a.w};
      float br[4] = {b.x, b.y, b.z, b.w};
      #pragma unroll
      for (int i = 0; i < 4; i++)
        #pragma unroll
        for (int j = 0; j < 4; j++) acc[i][j] += ar[i] * br[j];
    }
    __syncthreads();
  }
  #pragma unroll
  for (int i = 0; i < 4; i++) {
    int r = bm * 64 + ty * 4 + i;
    #pragma unroll
    for (int j = 0; j < 4; j++) {
      int c = bn * 64 + tx * 4 + j;
      if (c < N) C[(size_t)r * N + c] = acc[i][j];
    }
  }
}

// ---------------------------------------------------------------------------
// conv + SiLU + l2norm for q/k
// ---------------------------------------------------------------------------
__global__ __launch_bounds__(128) void conv_qk_kernel(
    const float* __restrict__ pre, const float* __restrict__ cw,
    float* __restrict__ out, float scale) {
  const int s = blockIdx.x, h = blockIdx.y, t = threadIdx.x;
  const int c = h * 128 + t;
  const float4 w = *(const float4*)&cw[c * 4];
  float y = pre[(size_t)s * KEY_DIM + c] * w.w;
  if (s >= 1) y += pre[(size_t)(s-1) * KEY_DIM + c] * w.z;
  if (s >= 2) y += pre[(size_t)(s-2) * KEY_DIM + c] * w.y;
  if (s >= 3) y += pre[(size_t)(s-3) * KEY_DIM + c] * w.x;
  float v = y / (1.f + expf(-y));
  float ss = v * v;
  #pragma unroll
  for (int off = 1; off < 64; off <<= 1) ss += __shfl_xor(ss, off, 64);
  __shared__ float red[2];
  if ((t & 63) == 0) red[t >> 6] = ss;
  __syncthreads();
  float inv = scale / sqrtf(red[0] + red[1] + 1e-6f);
  out[((size_t)s * NH + h) * 128 + t] = v * inv;
}

// ---------------------------------------------------------------------------
// conv + SiLU for v
// ---------------------------------------------------------------------------
__global__ __launch_bounds__(256) void conv_v_kernel(
    const float* __restrict__ pre, const float* __restrict__ cw,
    float* __restrict__ out) {
  const int id = blockIdx.x * 256 + threadIdx.x;
  const int s = id >> 11, c = id & 2047;
  const float4 w = *(const float4*)&cw[c * 4];
  float y = pre[id] * w.w;
  if (s >= 1) y += pre[id - VAL_DIM]     * w.z;
  if (s >= 2) y += pre[id - 2*VAL_DIM]   * w.y;
  if (s >= 3) y += pre[id - 3*VAL_DIM]   * w.x;
  out[id] = y / (1.f + expf(-y));
}

// ---------------------------------------------------------------------------
// gl = -exp(A_log)*softplus(a+dt_bias)  (LOG decay), beta = sigmoid(b)
// ---------------------------------------------------------------------------
__global__ __launch_bounds__(256) void gb_kernel(
    const float* __restrict__ a_pre, const float* __restrict__ b_pre,
    const float* __restrict__ A_log, const float* __restrict__ dt_bias,
    float* __restrict__ gl, float* __restrict__ bv) {
  const int id = blockIdx.x * 256 + threadIdx.x;
  const int h = id & 15;
  float av = a_pre[id] + dt_bias[h];
  float sp = av > 20.f ? av : log1pf(expf(av));
  gl[id] = -expf(A_log[h]) * sp;
  bv[id] = 1.f / (1.f + expf(-b_pre[id]));
}

// ---------------------------------------------------------------------------
// Phase A v2 (unchanged)
// ---------------------------------------------------------------------------
__global__ __launch_bounds__(256) void phaseA_kernel(
    const float* __restrict__ kn, const float* __restrict__ vc,
    const float* __restrict__ gl, const float* __restrict__ bvv,
    __hip_bfloat16* __restrict__ Wb, __hip_bfloat16* __restrict__ UbT,
    float* __restrict__ Gbuf) {
  const int h = blockIdx.x, c = blockIdx.y, sh = h >> 1;
  const int t = threadIdx.x;
  __shared__ float kchT[128][68];   // [dk][j]
  __shared__ float vch[64][132];    // [j][n]
  __shared__ float mm[64][65];
  __shared__ float sol[64][257];    // odd stride: conflict-free per-column
  __shared__ float Gs[64], bet[64], lamB[64];

  {
    const int r = t >> 2, c0 = (t & 3) * 32;
    const float* krow = kn + (size_t)(c*64 + r)*KEY_DIM + sh*128 + c0;
    const float* vrow = vc + (size_t)(c*64 + r)*VAL_DIM + h*128 + c0;
    #pragma unroll
    for (int i = 0; i < 8; i++) {
      float4 kv = *(const float4*)&krow[4*i];
      kchT[c0+4*i+0][r] = kv.x; kchT[c0+4*i+1][r] = kv.y;
      kchT[c0+4*i+2][r] = kv.z; kchT[c0+4*i+3][r] = kv.w;
      *(float4*)&vch[r][c0 + 4*i] = *(const float4*)&vrow[4*i];
    }
  }
  if (t < 64) {
    float g = gl[(size_t)(c*64 + t)*NVH + h];
    #pragma unroll
    for (int off = 1; off < 64; off <<= 1) {
      float p = __shfl_up(g, off, 64);
      if (t >= off) g += p;
    }
    Gs[t] = g;
    float b = bvv[(size_t)(c*64 + t)*NVH + h];
    bet[t] = b;
    lamB[t] = b * expf(g);
    Gbuf[((size_t)c*NVH + h)*64 + t] = g;
  }
  __syncthreads();

  {
    const int j0 = (t >> 4) * 4, l0 = (t & 15) * 4;
    float acc[4][4] = {};
    #pragma unroll 2
    for (int d = 0; d < 128; d++) {
      float4 kj = *(const float4*)&kchT[d][j0];
      float4 kl = *(const float4*)&kchT[d][l0];
      float aj[4] = {kj.x, kj.y, kj.z, kj.w};
      float al[4] = {kl.x, kl.y, kl.z, kl.w};
      #pragma unroll
      for (int i = 0; i < 4; i++)
        #pragma unroll
        for (int ii = 0; ii < 4; ii++)
          acc[i][ii] = fmaf(aj[i], al[ii], acc[i][ii]);
    }
    #pragma unroll
    for (int i = 0; i < 4; i++)
      #pragma unroll
      for (int ii = 0; ii < 4; ii++) {
        int j = j0 + i, l = l0 + ii;
        mm[j][l] = (l < j) ? bet[j] * expf(Gs[j] - Gs[l]) * acc[i][ii] : 0.f;
      }
  }
  __syncthreads();

  {
    const bool isW = t < 128;
    const int col = t & 127;
    for (int j = 0; j < 64; j++) {
      float s0 = isW ? lamB[j] * kchT[col][j] : bet[j] * vch[j][col];
      float s1 = 0.f;
      int l = 0;
      for (; l + 1 < j; l += 2) {
        s0 = fmaf(-mm[j][l],   sol[l][t],   s0);
        s1 = fmaf(-mm[j][l+1], sol[l+1][t], s1);
      }
      if (l < j) s0 = fmaf(-mm[j][l], sol[l][t], s0);
      sol[j][t] = s0 + s1;
    }
  }
  if (t < 128) {
    const size_t base = ((size_t)c*NVH + h) * 64 * 128;
    for (int j = 0; j < 64; j++)
      Wb[base + j*128 + t] = __float2bfloat16(sol[j][t]);
  } else {
    const int n = t - 128;
    const size_t ub = (((size_t)c*NVH + h) * 128 + n) * 64;
    for (int j0 = 0; j0 < 64; j0 += 4) {
      union { unsigned long long u; __hip_bfloat16 b[4]; } p;
      #pragma unroll
      for (int i = 0; i < 4; i++) p.b[i] = __float2bfloat16(sol[j0+i][t]);
      *(unsigned long long*)&UbT[ub + j0] = p.u;
    }
  }
}

// ---------------------------------------------------------------------------
// Phase B v4: lgkm-only raw barriers, 2 per chunk (was 3 __syncthreads).
// __syncthreads drains vmcnt(0)/expcnt(0) before s_barrier, which serialized
// the 26 prefetch loads + 32 scalar stores into the per-chunk critical path
// 3x per chunk. Dependence audit: q16 (phase1 A-op) and kT (update A-op) are
// written and read by the SAME wave (rows [16w,16w+16) / [32w,32w+32)) ->
// no barrier needed; only dT (epilogue->update) and S16T/Gs (mirror/stage ->
// next chunk's phase1/epilogue) are cross-wave -> 2 lgkmcnt(0)+s_barrier.
// Prefetch loads now drain only at stage() (register dep); stores drain
// lazily across chunks.
// ---------------------------------------------------------------------------
__device__ __forceinline__ void bar_lgkm() {
  asm volatile("s_waitcnt lgkmcnt(0)" ::: "memory");
  __builtin_amdgcn_s_barrier();
  asm volatile("" ::: "memory");
}

__global__ __launch_bounds__(256, 1) void phaseB_kernel(
    const float* __restrict__ qn, const float* __restrict__ kn,
    const __hip_bfloat16* __restrict__ Wb, const __hip_bfloat16* __restrict__ UbT,
    const float* __restrict__ Gbuf,
    __hip_bfloat16* __restrict__ Db, float* __restrict__ obuf) {
  const int h = blockIdx.x >> 1, vt = blockIdx.x & 1, sh = h >> 1;
  const int t = threadIdx.x, lane = t & 63, w = t >> 6;
  const int fm = lane & 15, fq = lane >> 4;

  __shared__ __hip_bfloat16 S16T[64][136];  // S0 mirror (bf16), [n_loc][dk]
  __shared__ __hip_bfloat16 kT[128][72];    // [dk][j]  (wave-local rows)
  __shared__ __hip_bfloat16 q16[64][136];   // e^{G_j} q, [j][dk] (wave-local rows)
  __shared__ __hip_bfloat16 dT[64][72];     // e^{G_C-G_j} Delta, [n_loc][j]
  __shared__ float Gs[64];

  // staging assignments
  const int qr = t >> 2, qc = (t & 3) * 32;          // q: one row, 32 cols
  const int kj = (t & 7) * 8, kd = (t >> 3) * 4;     // k: 8 rows x 4 dk (transpose)
  const int j0 = 16*w + fq*4;                        // epilogue rows

  f32x4 Sacc[2][4];
  #pragma unroll
  for (int ti = 0; ti < 2; ti++)
    #pragma unroll
    for (int tj = 0; tj < 4; tj++) Sacc[ti][tj] = (f32x4){0.f,0.f,0.f,0.f};
  for (int i = t; i < 64*136/2; i += 256) ((unsigned int*)S16T)[i] = 0;

  float4 qreg[8], kreg[8];
  short8 Wnext[4], Wcur[4];
  unsigned long long Unext[4], Ucur[4];
  float gq, gl64;

  auto prefetch = [&](int c) {
    const int cb = (c*NVH + h) * 64;
    const float* qrow = qn + (size_t)(c*64 + qr)*KEY_DIM + sh*128 + qc;
    #pragma unroll
    for (int i = 0; i < 8; i++) qreg[i] = *(const float4*)&qrow[4*i];
    #pragma unroll
    for (int jj = 0; jj < 8; jj++)
      kreg[jj] = *(const float4*)&kn[(size_t)(c*64 + kj + jj)*KEY_DIM + sh*128 + kd];
    #pragma unroll
    for (int k4 = 0; k4 < 4; k4++)
      Wnext[k4] = *(const short8*)&Wb[(size_t)(cb + 16*w + fm)*128 + k4*32 + fq*8];
    #pragma unroll
    for (int tj = 0; tj < 4; tj++)
      Unext[tj] = *(const unsigned long long*)
          &UbT[(((size_t)c*NVH + h)*128 + vt*64 + 16*tj + fm)*64 + j0];
    gq = Gbuf[(size_t)cb + qr];
    if (t < 64) gl64 = Gbuf[(size_t)cb + t];
  };

  auto stage = [&]() {
    if (t < 64) Gs[t] = gl64;
    const float eg = expf(gq);
    #pragma unroll
    for (int i = 0; i < 8; i++) {
      union { __hip_bfloat16 b[4]; unsigned long long u; } pq;
      pq.b[0] = __float2bfloat16(qreg[i].x * eg);
      pq.b[1] = __float2bfloat16(qreg[i].y * eg);
      pq.b[2] = __float2bfloat16(qreg[i].z * eg);
      pq.b[3] = __float2bfloat16(qreg[i].w * eg);
      *(unsigned long long*)&q16[qr][qc + 4*i] = pq.u;
    }
    const float* kf = (const float*)kreg;
    #pragma unroll
    for (int dd = 0; dd < 4; dd++) {
      union { __hip_bfloat16 b[8]; short8 s; } pk;
      #pragma unroll
      for (int jj = 0; jj < 8; jj++) pk.b[jj] = __float2bfloat16(kf[jj*4 + dd]);
      *(short8*)&kT[kd + dd][kj] = pk.s;
    }
  };

  prefetch(0);
  #pragma unroll
  for (int k4 = 0; k4 < 4; k4++) Wcur[k4] = Wnext[k4];
  #pragma unroll
  for (int tj = 0; tj < 4; tj++) Ucur[tj] = Unext[tj];
  bar_lgkm();               // S16T zero-init visible
  stage();
  bar_lgkm();               // chunk-0 staging + Gs visible

  for (int c = 0; c < NCH; c++) {
    // issue prefetch for c+1 (independent; drains at stage() at chunk end)
    prefetch(c + 1 < NCH ? c + 1 : 0);

    // (1)+(2): X = W S0, opart = q16 S0
    f32x4 aX[4], aO[4];
    #pragma unroll
    for (int tj = 0; tj < 4; tj++) {
      aX[tj] = (f32x4){0.f,0.f,0.f,0.f};
      aO[tj] = (f32x4){0.f,0.f,0.f,0.f};
    }
    #pragma unroll
    for (int k4 = 0; k4 < 4; k4++) {
      short8 aQ = *(const short8*)&q16[16*w + fm][k4*32 + fq*8];
      #pragma unroll
      for (int tj = 0; tj < 4; tj++) {
        short8 b = *(const short8*)&S16T[16*tj + fm][k4*32 + fq*8];
        aX[tj] = __builtin_amdgcn_mfma_f32_16x16x32_bf16(Wcur[k4], b, aX[tj], 0, 0, 0);
        aO[tj] = __builtin_amdgcn_mfma_f32_16x16x32_bf16(aQ,       b, aO[tj], 0, 0, 0);
      }
    }
    // epilogue: Delta, dT, stores
    const int cb = (c*NVH + h) * 64;
    const float gC = Gs[63];
    float er[4];
    #pragma unroll
    for (int r2 = 0; r2 < 4; r2++) er[r2] = expf(gC - Gs[j0 + r2]);
    #pragma unroll
    for (int tj = 0; tj < 4; tj++) {
      const int n = 16*tj + fm;
      union { unsigned long long u; __hip_bfloat16 b[4]; } u4;
      u4.u = Ucur[tj];
      union { __hip_bfloat16 b[4]; unsigned long long u; } pd;
      #pragma unroll
      for (int r2 = 0; r2 < 4; r2++) {
        const int j = j0 + r2;
        float d = __bfloat162float(u4.b[r2]) - aX[tj][r2];
        Db[(size_t)(cb + j)*128 + vt*64 + n] = __float2bfloat16(d);
        pd.b[r2] = __float2bfloat16(d * er[r2]);
        obuf[((size_t)(c*64 + j)*NVH + h)*128 + vt*64 + n] = aO[tj][r2];
      }
      *(unsigned long long*)&dT[n][j0] = pd.u;
    }
    // decay S
    const float lamC = expf(gC);
    #pragma unroll
    for (int ti = 0; ti < 2; ti++)
      #pragma unroll
      for (int tj = 0; tj < 4; tj++)
        #pragma unroll
        for (int r2 = 0; r2 < 4; r2++) Sacc[ti][tj][r2] *= lamC;
    // barrier A: dT visible; all phase-1 S16T reads + epilogue Gs reads done.
    // LDS-only drain: prefetch loads / global stores stay in flight.
    bar_lgkm();
    // (3): S += K^T dT'   (kT rows are wave-local; dT is cross-wave, covered by A)
    #pragma unroll
    for (int ti = 0; ti < 2; ti++) {
      const int m0 = 32*w + 16*ti;
      #pragma unroll
      for (int kk0 = 0; kk0 < 64; kk0 += 32) {
        short8 aK = *(const short8*)&kT[m0 + fm][kk0 + fq*8];
        #pragma unroll
        for (int tj = 0; tj < 4; tj++) {
          short8 bD = *(const short8*)&dT[16*tj + fm][kk0 + fq*8];
          Sacc[ti][tj] = __builtin_amdgcn_mfma_f32_16x16x32_bf16(aK, bD, Sacc[ti][tj], 0, 0, 0);
        }
      }
    }
    // refresh bf16 mirror
    #pragma unroll
    for (int ti = 0; ti < 2; ti++) {
      const int dk0 = 32*w + 16*ti + fq*4;
      #pragma unroll
      for (int tj = 0; tj < 4; tj++) {
        const int n = 16*tj + fm;
        union { __hip_bfloat16 b[4]; unsigned long long u; } ps;
        #pragma unroll
        for (int r2 = 0; r2 < 4; r2++) ps.b[r2] = __float2bfloat16(Sacc[ti][tj][r2]);
        *(unsigned long long*)&S16T[n][dk0] = ps.u;
      }
    }
    // stage c+1 regs -> LDS (q16/kT wave-local; Gs by wave 0, read next chunk)
    stage();
    #pragma unroll
    for (int k4 = 0; k4 < 4; k4++) Wcur[k4] = Wnext[k4];
    #pragma unroll
    for (int tj = 0; tj < 4; tj++) Ucur[tj] = Unext[tj];
    // barrier B: S16T mirror + Gs + staging visible for chunk c+1
    bar_lgkm();
  }
}

// ---------------------------------------------------------------------------
// Phase C (unchanged)
// ---------------------------------------------------------------------------
__global__ __launch_bounds__(256) void phaseC_kernel(
    const float* __restrict__ qn, const float* __restrict__ kn,
    const float* __restrict__ Gbuf, const __hip_bfloat16* __restrict__ Db,
    float* __restrict__ obuf) {
  const int h = blockIdx.x, c = blockIdx.y, sh = h >> 1;
  const int t = threadIdx.x;
  __shared__ float qch[64][132];
  __shared__ float kch[64][132];
  __shared__ float PT[64][68];              // [l][j]
  __shared__ __hip_bfloat16 dch[64][136];   // [l][n]
  __shared__ float Gs[64];

  {
    const int r = t >> 2, c0 = (t & 3) * 32;
    const float* qrow = qn + (size_t)(c*64 + r)*KEY_DIM + sh*128 + c0;
    const float* krow = kn + (size_t)(c*64 + r)*KEY_DIM + sh*128 + c0;
    #pragma unroll
    for (int i = 0; i < 8; i++) {
      *(float4*)&qch[r][c0 + 4*i] = *(const float4*)&qrow[4*i];
      *(float4*)&kch[r][c0 + 4*i] = *(const float4*)&krow[4*i];
    }
    const __hip_bfloat16* drow = Db + ((size_t)c*NVH + h)*64*128 + (size_t)r*128 + c0;
    #pragma unroll
    for (int i = 0; i < 4; i++)
      *(short8*)&dch[r][c0 + 8*i] = *(const short8*)&drow[8*i];
  }
  if (t < 64) Gs[t] = Gbuf[((size_t)c*NVH + h)*64 + t];
  __syncthreads();

  {
    const int jb = t >> 4, lb = t & 15;
    const int j0 = jb * 4, l0 = lb * 4;
    float acc[4][4] = {};
    for (int dd = 0; dd < 32; dd++) {
      const int d4 = ((dd + lb) & 31) * 4;
      float4 qj[4], kl[4];
      #pragma unroll
      for (int i = 0; i < 4; i++) {
        qj[i] = *(const float4*)&qch[j0 + i][d4];
        kl[i] = *(const float4*)&kch[l0 + i][d4];
      }
      #pragma unroll
      for (int i = 0; i < 4; i++)
        #pragma unroll
        for (int ii = 0; ii < 4; ii++)
          acc[i][ii] += qj[i].x*kl[ii].x + qj[i].y*kl[ii].y
                      + qj[i].z*kl[ii].z + qj[i].w*kl[ii].w;
    }
    #pragma unroll
    for (int i = 0; i < 4; i++)
      #pragma unroll
      for (int ii = 0; ii < 4; ii++) {
        int j = j0 + i, l = l0 + ii;
        PT[l][j] = (l <= j) ? expf(Gs[j] - Gs[l]) * acc[i][ii] : 0.f;
      }
  }
  __syncthreads();

  {
    const int j0 = (t >> 5) * 8;
    const int n0 = (t & 31) * 4;
    float acc2[8][4] = {};
    for (int l = 0; l < 64; l++) {
      float4 p0 = *(const float4*)&PT[l][j0];
      float4 p1 = *(const float4*)&PT[l][j0 + 4];
      float pj[8] = {p0.x,p0.y,p0.z,p0.w,p1.x,p1.y,p1.z,p1.w};
      float dv[4];
      #pragma unroll
      for (int ii = 0; ii < 4; ii++) dv[ii] = __bfloat162float(dch[l][n0 + ii]);
      #pragma unroll
      for (int i = 0; i < 8; i++)
        #pragma unroll
        for (int ii = 0; ii < 4; ii++)
          acc2[i][ii] += pj[i] * dv[ii];
    }
    #pragma unroll
    for (int i = 0; i < 8; i++) {
      float* orow = obuf + ((size_t)(c*64 + j0 + i)*NVH + h)*128 + n0;
      float4 o4 = *(const float4*)orow;
      o4.x += acc2[i][0]; o4.y += acc2[i][1];
      o4.z += acc2[i][2]; o4.w += acc2[i][3];
      *(float4*)orow = o4;
    }
  }
}

// ---------------------------------------------------------------------------
// Gated RMSNorm -> bf16
// ---------------------------------------------------------------------------
__global__ __launch_bounds__(128) void norm_kernel(
    const float* __restrict__ o, const float* __restrict__ gate,
    const float* __restrict__ w_norm, __hip_bfloat16* __restrict__ og) {
  const int s = blockIdx.x, h = blockIdx.y, t = threadIdx.x;
  const size_t idx = (size_t)s * VAL_DIM + h * 128 + t;
  float gt = gate[idx];
  float val = o[idx] * (gt / (1.f + expf(-gt)));
  float ss = val * val;
  #pragma unroll
  for (int off = 1; off < 64; off <<= 1) ss += __shfl_xor(ss, off, 64);
  __shared__ float red[2];
  if ((t & 63) == 0) red[t >> 6] = ss;
  __syncthreads();
  float ms = (red[0] + red[1]) * (1.f / 128.f);
  og[idx] = __float2bfloat16(val * (1.f / sqrtf(ms + 1e-6f)) * w_norm[t]);
}

// ---------------------------------------------------------------------------
extern "C" void kernel_launch(void* const* d_in, const int* in_sizes, int n_in,
                              void* d_out, int out_size, void* d_ws, size_t ws_size,
                              hipStream_t stream) {
  const float* x       = (const float*)d_in[0];
  const float* Wq      = (const float*)d_in[1];
  const float* Wk      = (const float*)d_in[2];
  const float* Wv      = (const float*)d_in[3];
  const float* Wa      = (const float*)d_in[4];
  const float* Wb_     = (const float*)d_in[5];
  const float* Wg      = (const float*)d_in[6];
  const float* Wo      = (const float*)d_in[7];
  const float* conv_q  = (const float*)d_in[8];
  const float* conv_k  = (const float*)d_in[9];
  const float* conv_v  = (const float*)d_in[10];
  const float* A_log   = (const float*)d_in[11];
  const float* dt_bias = (const float*)d_in[12];
  const float* w_norm  = (const float*)d_in[13];
  float* out = (float*)d_out;

  const size_t QK = (size_t)S_LEN * KEY_DIM;   // 4.19M
  const size_t SV = (size_t)S_LEN * VAL_DIM;   // 8.39M
  const size_t SM = (size_t)S_LEN * NVH;       // 65536

  float* W = (float*)d_ws;
  float* q_pre = W;
  float* k_pre = q_pre + QK;
  float* v_pre = k_pre + QK;       // SV floats; later: UbT (bf16) | Db (bf16)
  float* qn    = v_pre + SV;
  float* kn    = qn + QK;
  float* vcb   = kn + QK;          // SV floats; later: obuf
  float* a_pre = vcb + SV;
  float* b_pre = a_pre + SM;
  float* glb   = b_pre + SM;
  float* beta  = glb + SM;
  float* Gbuf  = beta + SM;        // NCH*NVH*64 = 65536
  __hip_bfloat16* xb = (__hip_bfloat16*)(Gbuf + SM);  // 8.39M bf16; later: Wb
  __hip_bfloat16* wb = xb + SV;                       // up to 4.19M bf16

  float* gate = q_pre;             // after convs
  float* obuf = vcb;               // after phase A
  __hip_bfloat16* ogb = (__hip_bfloat16*)kn;  // norm output
  __hip_bfloat16* Wbb = xb;                   // after gate gemm
  __hip_bfloat16* UbT = (__hip_bfloat16*)v_pre;
  __hip_bfloat16* Db  = (__hip_bfloat16*)(v_pre + SV/2);

  const int NC = 256 * 4;
  cast_f2b<<<(S_LEN*HID)/NC, 256, 0, stream>>>(x, xb, S_LEN*HID);

  cast_f2b<<<(KEY_DIM*HID)/NC, 256, 0, stream>>>(Wq, wb, KEY_DIM*HID);
  gemm_bf16_bt<<<dim3(KEY_DIM/128, S_LEN/128), 256, 0, stream>>>(xb, wb, q_pre, S_LEN, KEY_DIM, HID);
  cast_f2b<<<(KEY_DIM*HID)/NC, 256, 0, stream>>>(Wk, wb, KEY_DIM*HID);
  gemm_bf16_bt<<<dim3(KEY_DIM/128, S_LEN/128), 256, 0, stream>>>(xb, wb, k_pre, S_LEN, KEY_DIM, HID);
  cast_f2b<<<(VAL_DIM*HID)/NC, 256, 0, stream>>>(Wv, wb, VAL_DIM*HID);
  gemm_bf16_bt<<<dim3(VAL_DIM/128, S_LEN/128), 256, 0, stream>>>(xb, wb, v_pre, S_LEN, VAL_DIM, HID);
  gemm_bt<<<dim3(1, S_LEN/64), 256, 0, stream>>>(x, Wa, a_pre, S_LEN, NVH, HID);
  gemm_bt<<<dim3(1, S_LEN/64), 256, 0, stream>>>(x, Wb_, b_pre, S_LEN, NVH, HID);

  conv_qk_kernel<<<dim3(S_LEN, NH), 128, 0, stream>>>(q_pre, conv_q, qn, SCALE_Q);
  conv_qk_kernel<<<dim3(S_LEN, NH), 128, 0, stream>>>(k_pre, conv_k, kn, 1.f);
  conv_v_kernel<<<(S_LEN*VAL_DIM)/256, 256, 0, stream>>>(v_pre, conv_v, vcb);
  gb_kernel<<<(S_LEN*NVH)/256, 256, 0, stream>>>(a_pre, b_pre, A_log, dt_bias, glb, beta);

  cast_f2b<<<(VAL_DIM*HID)/NC, 256, 0, stream>>>(Wg, wb, VAL_DIM*HID);
  gemm_bf16_bt<<<dim3(VAL_DIM/128, S_LEN/128), 256, 0, stream>>>(xb, wb, gate, S_LEN, VAL_DIM, HID);

  // chunked delta-rule scan
  phaseA_kernel<<<dim3(NVH, NCH), 256, 0, stream>>>(kn, vcb, glb, beta, Wbb, UbT, Gbuf);
  phaseB_kernel<<<2*NVH, 256, 0, stream>>>(qn, kn, Wbb, UbT, Gbuf, Db, obuf);
  phaseC_kernel<<<dim3(NVH, NCH), 256, 0, stream>>>(qn, kn, Gbuf, Db, obuf);

  norm_kernel<<<dim3(S_LEN, NVH), 128, 0, stream>>>(obuf, gate, w_norm, ogb);

  cast_f2b<<<(HID*VAL_DIM)/NC, 256, 0, stream>>>(Wo, wb, HID*VAL_DIM);
  gemm_bf16_bt<<<dim3(HID/128, S_LEN/128), 256, 0, stream>>>(ogb, wb, out, S_LEN, HID, VAL_DIM);
}

// Round 2
// 1268.801 us; speedup vs baseline: 1.0217x; 1.0171x over previous
//
#include <hip/hip_runtime.h>
#include <hip/hip_bf16.h>
#include <math.h>

#define S_LEN 4096
#define HID   2048
#define NH    8
#define NVH   16
#define DK    128
#define DV    128
#define KEY_DIM  (NH*DK)    // 1024
#define VAL_DIM  (NVH*DV)   // 2048
#define SCALE_Q  0.08838834764831845f  // 128^-0.5
#define CCH 64              // chunk length
#define NCH (S_LEN/CCH)     // 64 chunks

typedef __attribute__((ext_vector_type(8))) short short8;   // 8 bf16
typedef __attribute__((ext_vector_type(4))) float f32x4;

// ---------------------------------------------------------------------------
// float -> bf16 cast
// ---------------------------------------------------------------------------
__global__ __launch_bounds__(256) void cast_f2b(
    const float* __restrict__ in, __hip_bfloat16* __restrict__ out, int n) {
  int i = (blockIdx.x * 256 + threadIdx.x) * 4;
  if (i >= n) return;
  float4 v = *(const float4*)&in[i];
  union { __hip_bfloat16 b[4]; short4 s; } u;
  u.b[0] = __float2bfloat16(v.x); u.b[1] = __float2bfloat16(v.y);
  u.b[2] = __float2bfloat16(v.z); u.b[3] = __float2bfloat16(v.w);
  *(short4*)&out[i] = u.s;
}

// ---------------------------------------------------------------------------
// bf16 MFMA GEMM: C[M,N](fp32) = A[M,K] @ B[N,K]^T  (m97 structure)
// ---------------------------------------------------------------------------
__device__ __forceinline__ void lds_load16(const __hip_bfloat16* g,
                                           __hip_bfloat16* l) {
  __builtin_amdgcn_global_load_lds(
      (const __attribute__((address_space(1))) unsigned int*)g,
      (__attribute__((address_space(3))) unsigned int*)l, 16, 0, 0);
}

__global__ __launch_bounds__(256) void gemm_bf16_bt(
    const __hip_bfloat16* __restrict__ A, const __hip_bfloat16* __restrict__ B,
    float* __restrict__ C, int M, int N, int K) {
  __shared__ __hip_bfloat16 sA[128 * 32];
  __shared__ __hip_bfloat16 sB[128 * 32];
  const int t = threadIdx.x;
  const int wave = t >> 6, lane = t & 63;
  const int bm = blockIdx.y, bn = blockIdx.x;
  const int wm = (wave & 1) * 64, wn = (wave >> 1) * 64;

  f32x4 zero = {0.f, 0.f, 0.f, 0.f};
  f32x4 acc[4][4];
  #pragma unroll
  for (int i = 0; i < 4; i++)
    #pragma unroll
    for (int j = 0; j < 4; j++) acc[i][j] = zero;

  const int r0 = t >> 2,        c0 = (t & 3) * 8;
  const int r1 = (256 + t) >> 2, c1 = ((256 + t) & 3) * 8;
  const __hip_bfloat16* gA0 = A + (size_t)(bm * 128 + r0) * K + c0;
  const __hip_bfloat16* gA1 = A + (size_t)(bm * 128 + r1) * K + c1;
  const __hip_bfloat16* gB0 = B + (size_t)(bn * 128 + r0) * K + c0;
  const __hip_bfloat16* gB1 = B + (size_t)(bn * 128 + r1) * K + c1;
  __hip_bfloat16* lA0 = sA + (size_t)(wave * 64) * 8;
  __hip_bfloat16* lA1 = sA + (size_t)(256 + wave * 64) * 8;
  __hip_bfloat16* lB0 = sB + (size_t)(wave * 64) * 8;
  __hip_bfloat16* lB1 = sB + (size_t)(256 + wave * 64) * 8;

  const int fm = lane & 15, fk = (lane >> 4) * 8;

  for (int k0 = 0; k0 < K; k0 += 32) {
    lds_load16(gA0, lA0); lds_load16(gA1, lA1);
    lds_load16(gB0, lB0); lds_load16(gB1, lB1);
    gA0 += 32; gA1 += 32; gB0 += 32; gB1 += 32;
    __syncthreads();
    short8 a[4], b[4];
    #pragma unroll
    for (int i = 0; i < 4; i++)
      a[i] = *(const short8*)&sA[(size_t)(wm + i * 16 + fm) * 32 + fk];
    #pragma unroll
    for (int j = 0; j < 4; j++)
      b[j] = *(const short8*)&sB[(size_t)(wn + j * 16 + fm) * 32 + fk];
    #pragma unroll
    for (int i = 0; i < 4; i++)
      #pragma unroll
      for (int j = 0; j < 4; j++)
        acc[i][j] = __builtin_amdgcn_mfma_f32_16x16x32_bf16(a[i], b[j], acc[i][j], 0, 0, 0);
    __syncthreads();
  }
  #pragma unroll
  for (int i = 0; i < 4; i++) {
    #pragma unroll
    for (int j = 0; j < 4; j++) {
      int col = bn * 128 + wn + j * 16 + (lane & 15);
      int rw0 = bm * 128 + wm + i * 16 + (lane >> 4) * 4;
      #pragma unroll
      for (int r = 0; r < 4; r++)
        C[(size_t)(rw0 + r) * N + col] = acc[i][j][r];
    }
  }
}

// ---------------------------------------------------------------------------
// fp32 GEMM for the tiny N=16 projections (Wa, Wb)
// ---------------------------------------------------------------------------
__global__ __launch_bounds__(256) void gemm_bt(
    const float* __restrict__ A, const float* __restrict__ B,
    float* __restrict__ C, int M, int N, int K) {
  __shared__ float As[16][68];
  __shared__ float Bs[16][68];
  const int bm = blockIdx.y, bn = blockIdx.x;
  const int t = threadIdx.x;
  const int tx = t & 15, ty = t >> 4;
  const int lrow = t >> 2;
  const int lk0  = (t & 3) * 4;
  const int arow = bm * 64 + lrow;
  const int brow = bn * 64 + lrow;
  const bool bvalid = brow < N;

  float acc[4][4];
  #pragma unroll
  for (int i = 0; i < 4; i++)
    #pragma unroll
    for (int j = 0; j < 4; j++) acc[i][j] = 0.f;

  for (int k0 = 0; k0 < K; k0 += 16) {
    float4 av = *(const float4*)&A[(size_t)arow * K + k0 + lk0];
    float4 bv = bvalid ? *(const float4*)&B[(size_t)brow * K + k0 + lk0]
                       : make_float4(0.f, 0.f, 0.f, 0.f);
    As[lk0+0][lrow] = av.x; As[lk0+1][lrow] = av.y;
    As[lk0+2][lrow] = av.z; As[lk0+3][lrow] = av.w;
    Bs[lk0+0][lrow] = bv.x; Bs[lk0+1][lrow] = bv.y;
    Bs[lk0+2][lrow] = bv.z; Bs[lk0+3][lrow] = bv.w;
    __syncthreads();
    #pragma unroll
    for (int kk = 0; kk < 16; kk++) {
      float4 a = *(const float4*)&As[kk][ty * 4];
      float4 b = *(const float4*)&Bs[kk][tx * 4];
      float ar[4] = {a.x, a.y, a.z, a.w};
      float br[4] = {b.x, b.y, b.z, b.w};
      #pragma unroll
      for (int i = 0; i < 4; i++)
        #pragma unroll
        for (int j = 0; j < 4; j++) acc[i][j] += ar[i] * br[j];
    }
    __syncthreads();
  }
  #pragma unroll
  for (int i = 0; i < 4; i++) {
    int r = bm * 64 + ty * 4 + i;
    #pragma unroll
    for (int j = 0; j < 4; j++) {
      int c = bn * 64 + tx * 4 + j;
      if (c < N) C[(size_t)r * N + c] = acc[i][j];
    }
  }
}

// ---------------------------------------------------------------------------
// conv + SiLU + l2norm for q/k
// ---------------------------------------------------------------------------
__global__ __launch_bounds__(128) void conv_qk_kernel(
    const float* __restrict__ pre, const float* __restrict__ cw,
    float* __restrict__ out, float scale) {
  const int s = blockIdx.x, h = blockIdx.y, t = threadIdx.x;
  const int c = h * 128 + t;
  const float4 w = *(const float4*)&cw[c * 4];
  float y = pre[(size_t)s * KEY_DIM + c] * w.w;
  if (s >= 1) y += pre[(size_t)(s-1) * KEY_DIM + c] * w.z;
  if (s >= 2) y += pre[(size_t)(s-2) * KEY_DIM + c] * w.y;
  if (s >= 3) y += pre[(size_t)(s-3) * KEY_DIM + c] * w.x;
  float v = y / (1.f + expf(-y));
  float ss = v * v;
  #pragma unroll
  for (int off = 1; off < 64; off <<= 1) ss += __shfl_xor(ss, off, 64);
  __shared__ float red[2];
  if ((t & 63) == 0) red[t >> 6] = ss;
  __syncthreads();
  float inv = scale / sqrtf(red[0] + red[1] + 1e-6f);
  out[((size_t)s * NH + h) * 128 + t] = v * inv;
}

// ---------------------------------------------------------------------------
// conv + SiLU for v
// ---------------------------------------------------------------------------
__global__ __launch_bounds__(256) void conv_v_kernel(
    const float* __restrict__ pre, const float* __restrict__ cw,
    float* __restrict__ out) {
  const int id = blockIdx.x * 256 + threadIdx.x;
  const int s = id >> 11, c = id & 2047;
  const float4 w = *(const float4*)&cw[c * 4];
  float y = pre[id] * w.w;
  if (s >= 1) y += pre[id - VAL_DIM]     * w.z;
  if (s >= 2) y += pre[id - 2*VAL_DIM]   * w.y;
  if (s >= 3) y += pre[id - 3*VAL_DIM]   * w.x;
  out[id] = y / (1.f + expf(-y));
}

// ---------------------------------------------------------------------------
// gl = -exp(A_log)*softplus(a+dt_bias)  (LOG decay), beta = sigmoid(b)
// ---------------------------------------------------------------------------
__global__ __launch_bounds__(256) void gb_kernel(
    const float* __restrict__ a_pre, const float* __restrict__ b_pre,
    const float* __restrict__ A_log, const float* __restrict__ dt_bias,
    float* __restrict__ gl, float* __restrict__ bv) {
  const int id = blockIdx.x * 256 + threadIdx.x;
  const int h = id & 15;
  float av = a_pre[id] + dt_bias[h];
  float sp = av > 20.f ? av : log1pf(expf(av));
  gl[id] = -expf(A_log[h]) * sp;
  bv[id] = 1.f / (1.f + expf(-b_pre[id]));
}

// ---------------------------------------------------------------------------
// Phase A v2 (unchanged)
// ---------------------------------------------------------------------------
__global__ __launch_bounds__(256) void phaseA_kernel(
    const float* __restrict__ kn, const float* __restrict__ vc,
    const float* __restrict__ gl, const float* __restrict__ bvv,
    __hip_bfloat16* __restrict__ Wb, __hip_bfloat16* __restrict__ UbT,
    float* __restrict__ Gbuf) {
  const int h = blockIdx.x, c = blockIdx.y, sh = h >> 1;
  const int t = threadIdx.x;
  __shared__ float kchT[128][68];   // [dk][j]
  __shared__ float vch[64][132];    // [j][n]
  __shared__ float mm[64][65];
  __shared__ float sol[64][257];    // odd stride: conflict-free per-column
  __shared__ float Gs[64], bet[64], lamB[64];

  {
    const int r = t >> 2, c0 = (t & 3) * 32;
    const float* krow = kn + (size_t)(c*64 + r)*KEY_DIM + sh*128 + c0;
    const float* vrow = vc + (size_t)(c*64 + r)*VAL_DIM + h*128 + c0;
    #pragma unroll
    for (int i = 0; i < 8; i++) {
      float4 kv = *(const float4*)&krow[4*i];
      kchT[c0+4*i+0][r] = kv.x; kchT[c0+4*i+1][r] = kv.y;
      kchT[c0+4*i+2][r] = kv.z; kchT[c0+4*i+3][r] = kv.w;
      *(float4*)&vch[r][c0 + 4*i] = *(const float4*)&vrow[4*i];
    }
  }
  if (t < 64) {
    float g = gl[(size_t)(c*64 + t)*NVH + h];
    #pragma unroll
    for (int off = 1; off < 64; off <<= 1) {
      float p = __shfl_up(g, off, 64);
      if (t >= off) g += p;
    }
    Gs[t] = g;
    float b = bvv[(size_t)(c*64 + t)*NVH + h];
    bet[t] = b;
    lamB[t] = b * expf(g);
    Gbuf[((size_t)c*NVH + h)*64 + t] = g;
  }
  __syncthreads();

  {
    const int j0 = (t >> 4) * 4, l0 = (t & 15) * 4;
    float acc[4][4] = {};
    #pragma unroll 2
    for (int d = 0; d < 128; d++) {
      float4 kj = *(const float4*)&kchT[d][j0];
      float4 kl = *(const float4*)&kchT[d][l0];
      float aj[4] = {kj.x, kj.y, kj.z, kj.w};
      float al[4] = {kl.x, kl.y, kl.z, kl.w};
      #pragma unroll
      for (int i = 0; i < 4; i++)
        #pragma unroll
        for (int ii = 0; ii < 4; ii++)
          acc[i][ii] = fmaf(aj[i], al[ii], acc[i][ii]);
    }
    #pragma unroll
    for (int i = 0; i < 4; i++)
      #pragma unroll
      for (int ii = 0; ii < 4; ii++) {
        int j = j0 + i, l = l0 + ii;
        mm[j][l] = (l < j) ? bet[j] * expf(Gs[j] - Gs[l]) * acc[i][ii] : 0.f;
      }
  }
  __syncthreads();

  {
    const bool isW = t < 128;
    const int col = t & 127;
    for (int j = 0; j < 64; j++) {
      float s0 = isW ? lamB[j] * kchT[col][j] : bet[j] * vch[j][col];
      float s1 = 0.f;
      int l = 0;
      for (; l + 1 < j; l += 2) {
        s0 = fmaf(-mm[j][l],   sol[l][t],   s0);
        s1 = fmaf(-mm[j][l+1], sol[l+1][t], s1);
      }
      if (l < j) s0 = fmaf(-mm[j][l], sol[l][t], s0);
      sol[j][t] = s0 + s1;
    }
  }
  if (t < 128) {
    const size_t base = ((size_t)c*NVH + h) * 64 * 128;
    for (int j = 0; j < 64; j++)
      Wb[base + j*128 + t] = __float2bfloat16(sol[j][t]);
  } else {
    const int n = t - 128;
    const size_t ub = (((size_t)c*NVH + h) * 128 + n) * 64;
    for (int j0 = 0; j0 < 64; j0 += 4) {
      union { unsigned long long u; __hip_bfloat16 b[4]; } p;
      #pragma unroll
      for (int i = 0; i < 4; i++) p.b[i] = __float2bfloat16(sol[j0+i][t]);
      *(unsigned long long*)&UbT[ub + j0] = p.u;
    }
  }
}

// ---------------------------------------------------------------------------
// Phase B v5: 512 threads (8 waves, 2 waves/SIMD). R1 post-mortem: removing
// vmcnt drains gained only 3% -> per-chunk cost is issue + exposed latency at
// 1 wave/SIMD (active-CU VALUBusy ~20%, MFMA ~7%, 73% no-issue). Fix: halve
// per-wave work and double waves/SIMD so the HW scheduler interleaves stalls.
// Wave decomposition: phase-1 wave=(j-tile jt, n-half nh): 16 MFMAs/wave;
// update wave=(dk-tile dt, n-half nh): 8 MFMAs/wave. Same LDS buffers, same
// 2 lgkm-only barriers/chunk. s_setprio(1) around MFMA clusters (T5: now
// there are 2 waves/SIMD to arbitrate).
// ---------------------------------------------------------------------------
__device__ __forceinline__ void bar_lgkm() {
  asm volatile("s_waitcnt lgkmcnt(0)" ::: "memory");
  __builtin_amdgcn_s_barrier();
  asm volatile("" ::: "memory");
}

__global__ __launch_bounds__(512, 2) void phaseB_kernel(
    const float* __restrict__ qn, const float* __restrict__ kn,
    const __hip_bfloat16* __restrict__ Wb, const __hip_bfloat16* __restrict__ UbT,
    const float* __restrict__ Gbuf,
    __hip_bfloat16* __restrict__ Db, float* __restrict__ obuf) {
  const int h = blockIdx.x >> 1, vt = blockIdx.x & 1, sh = h >> 1;
  const int t = threadIdx.x, lane = t & 63, w = t >> 6;   // w 0..7
  const int fm = lane & 15, fq = lane >> 4;
  const int jt = w >> 1;          // j-tile (16 rows) for phase-1 / epilogue
  const int nh = w & 1;           // n-half: tj in {2nh, 2nh+1}
  const int dt = w >> 1;          // dk-tile (32 rows) for update/mirror

  __shared__ __hip_bfloat16 S16T[64][136];  // S0 mirror (bf16), [n_loc][dk]
  __shared__ __hip_bfloat16 kT[128][72];    // [dk][j]
  __shared__ __hip_bfloat16 q16[64][136];   // e^{G_j} q, [j][dk]
  __shared__ __hip_bfloat16 dT[64][72];     // e^{G_C-G_j} Delta, [n_loc][j]
  __shared__ float Gs[64];

  // staging assignments (512 threads)
  const int qr = t >> 3, qc = (t & 7) * 16;      // q: one row, 16 cols
  const int kj = (t & 15) * 4, kd = (t >> 4) * 4; // k: 4 j-rows x 4 dk (transpose)
  const int j0 = 16*jt + fq*4;                    // epilogue rows

  f32x4 Sacc[2][2];
  #pragma unroll
  for (int ti = 0; ti < 2; ti++)
    #pragma unroll
    for (int i = 0; i < 2; i++) Sacc[ti][i] = (f32x4){0.f,0.f,0.f,0.f};
  for (int i = t; i < 64*136/2; i += 512) ((unsigned int*)S16T)[i] = 0;

  float4 qreg[4], kreg[4];
  short8 Wnext[4], Wcur[4];
  unsigned long long Unext[2], Ucur[2];
  float gq, gl64;

  auto prefetch = [&](int c) {
    const int cb = (c*NVH + h) * 64;
    const float* qrow = qn + (size_t)(c*64 + qr)*KEY_DIM + sh*128 + qc;
    #pragma unroll
    for (int i = 0; i < 4; i++) qreg[i] = *(const float4*)&qrow[4*i];
    #pragma unroll
    for (int jj = 0; jj < 4; jj++)
      kreg[jj] = *(const float4*)&kn[(size_t)(c*64 + kj + jj)*KEY_DIM + sh*128 + kd];
    #pragma unroll
    for (int k4 = 0; k4 < 4; k4++)
      Wnext[k4] = *(const short8*)&Wb[(size_t)(cb + 16*jt + fm)*128 + k4*32 + fq*8];
    #pragma unroll
    for (int i = 0; i < 2; i++) {
      const int tj = 2*nh + i;
      Unext[i] = *(const unsigned long long*)
          &UbT[(((size_t)c*NVH + h)*128 + vt*64 + 16*tj + fm)*64 + j0];
    }
    gq = Gbuf[(size_t)cb + qr];
    if (t < 64) gl64 = Gbuf[(size_t)cb + t];
  };

  auto stage = [&]() {
    if (t < 64) Gs[t] = gl64;
    const float eg = expf(gq);
    #pragma unroll
    for (int i = 0; i < 4; i++) {
      union { __hip_bfloat16 b[4]; unsigned long long u; } pq;
      pq.b[0] = __float2bfloat16(qreg[i].x * eg);
      pq.b[1] = __float2bfloat16(qreg[i].y * eg);
      pq.b[2] = __float2bfloat16(qreg[i].z * eg);
      pq.b[3] = __float2bfloat16(qreg[i].w * eg);
      *(unsigned long long*)&q16[qr][qc + 4*i] = pq.u;
    }
    const float* kf = (const float*)kreg;
    #pragma unroll
    for (int dd = 0; dd < 4; dd++) {
      union { __hip_bfloat16 b[4]; unsigned long long u; } pk;
      #pragma unroll
      for (int jj = 0; jj < 4; jj++) pk.b[jj] = __float2bfloat16(kf[jj*4 + dd]);
      *(unsigned long long*)&kT[kd + dd][kj] = pk.u;
    }
  };

  prefetch(0);
  #pragma unroll
  for (int k4 = 0; k4 < 4; k4++) Wcur[k4] = Wnext[k4];
  #pragma unroll
  for (int i = 0; i < 2; i++) Ucur[i] = Unext[i];
  bar_lgkm();               // S16T zero-init visible
  stage();
  bar_lgkm();               // chunk-0 staging + Gs visible

  for (int c = 0; c < NCH; c++) {
    // issue prefetch for c+1 (independent; drains at stage() at chunk end)
    prefetch(c + 1 < NCH ? c + 1 : 0);

    // (1)+(2): X = W S0, opart = q16 S0    (wave covers j-tile jt x n-half nh)
    f32x4 aX[2], aO[2];
    #pragma unroll
    for (int i = 0; i < 2; i++) {
      aX[i] = (f32x4){0.f,0.f,0.f,0.f};
      aO[i] = (f32x4){0.f,0.f,0.f,0.f};
    }
    __builtin_amdgcn_s_setprio(1);
    #pragma unroll
    for (int k4 = 0; k4 < 4; k4++) {
      short8 aQ = *(const short8*)&q16[16*jt + fm][k4*32 + fq*8];
      #pragma unroll
      for (int i = 0; i < 2; i++) {
        const int tj = 2*nh + i;
        short8 b = *(const short8*)&S16T[16*tj + fm][k4*32 + fq*8];
        aX[i] = __builtin_amdgcn_mfma_f32_16x16x32_bf16(Wcur[k4], b, aX[i], 0, 0, 0);
        aO[i] = __builtin_amdgcn_mfma_f32_16x16x32_bf16(aQ,       b, aO[i], 0, 0, 0);
      }
    }
    __builtin_amdgcn_s_setprio(0);
    // epilogue: Delta, dT, stores
    const int cb = (c*NVH + h) * 64;
    const float gC = Gs[63];
    float er[4];
    #pragma unroll
    for (int r2 = 0; r2 < 4; r2++) er[r2] = expf(gC - Gs[j0 + r2]);
    #pragma unroll
    for (int i = 0; i < 2; i++) {
      const int tj = 2*nh + i;
      const int n = 16*tj + fm;
      union { unsigned long long u; __hip_bfloat16 b[4]; } u4;
      u4.u = Ucur[i];
      union { __hip_bfloat16 b[4]; unsigned long long u; } pd;
      #pragma unroll
      for (int r2 = 0; r2 < 4; r2++) {
        const int j = j0 + r2;
        float d = __bfloat162float(u4.b[r2]) - aX[i][r2];
        Db[(size_t)(cb + j)*128 + vt*64 + n] = __float2bfloat16(d);
        pd.b[r2] = __float2bfloat16(d * er[r2]);
        obuf[((size_t)(c*64 + j)*NVH + h)*128 + vt*64 + n] = aO[i][r2];
      }
      *(unsigned long long*)&dT[n][j0] = pd.u;
    }
    // decay S
    const float lamC = expf(gC);
    #pragma unroll
    for (int ti = 0; ti < 2; ti++)
      #pragma unroll
      for (int i = 0; i < 2; i++)
        #pragma unroll
        for (int r2 = 0; r2 < 4; r2++) Sacc[ti][i][r2] *= lamC;
    // barrier A: dT visible; all phase-1 S16T reads + epilogue Gs reads done.
    bar_lgkm();
    // (3): S += K^T dT'   (wave covers dk-tile dt x n-half nh)
    __builtin_amdgcn_s_setprio(1);
    #pragma unroll
    for (int ti = 0; ti < 2; ti++) {
      const int m0 = 32*dt + 16*ti;
      #pragma unroll
      for (int kk0 = 0; kk0 < 64; kk0 += 32) {
        short8 aK = *(const short8*)&kT[m0 + fm][kk0 + fq*8];
        #pragma unroll
        for (int i = 0; i < 2; i++) {
          const int tj = 2*nh + i;
          short8 bD = *(const short8*)&dT[16*tj + fm][kk0 + fq*8];
          Sacc[ti][i] = __builtin_amdgcn_mfma_f32_16x16x32_bf16(aK, bD, Sacc[ti][i], 0, 0, 0);
        }
      }
    }
    __builtin_amdgcn_s_setprio(0);
    // refresh bf16 mirror (cols 32dt..32dt+32, rows n in this wave's n-half)
    #pragma unroll
    for (int ti = 0; ti < 2; ti++) {
      const int dk0 = 32*dt + 16*ti + fq*4;
      #pragma unroll
      for (int i = 0; i < 2; i++) {
        const int tj = 2*nh + i;
        const int n = 16*tj + fm;
        union { __hip_bfloat16 b[4]; unsigned long long u; } ps;
        #pragma unroll
        for (int r2 = 0; r2 < 4; r2++) ps.b[r2] = __float2bfloat16(Sacc[ti][i][r2]);
        *(unsigned long long*)&S16T[n][dk0] = ps.u;
      }
    }
    // stage c+1 regs -> LDS
    stage();
    #pragma unroll
    for (int k4 = 0; k4 < 4; k4++) Wcur[k4] = Wnext[k4];
    #pragma unroll
    for (int i = 0; i < 2; i++) Ucur[i] = Unext[i];
    // barrier B: S16T mirror + Gs + staging visible for chunk c+1
    bar_lgkm();
  }
}

// ---------------------------------------------------------------------------
// Phase C (unchanged)
// ---------------------------------------------------------------------------
__global__ __launch_bounds__(256) void phaseC_kernel(
    const float* __restrict__ qn, const float* __restrict__ kn,
    const float* __restrict__ Gbuf, const __hip_bfloat16* __restrict__ Db,
    float* __restrict__ obuf) {
  const int h = blockIdx.x, c = blockIdx.y, sh = h >> 1;
  const int t = threadIdx.x;
  __shared__ float qch[64][132];
  __shared__ float kch[64][132];
  __shared__ float PT[64][68];              // [l][j]
  __shared__ __hip_bfloat16 dch[64][136];   // [l][n]
  __shared__ float Gs[64];

  {
    const int r = t >> 2, c0 = (t & 3) * 32;
    const float* qrow = qn + (size_t)(c*64 + r)*KEY_DIM + sh*128 + c0;
    const float* krow = kn + (size_t)(c*64 + r)*KEY_DIM + sh*128 + c0;
    #pragma unroll
    for (int i = 0; i < 8; i++) {
      *(float4*)&qch[r][c0 + 4*i] = *(const float4*)&qrow[4*i];
      *(float4*)&kch[r][c0 + 4*i] = *(const float4*)&krow[4*i];
    }
    const __hip_bfloat16* drow = Db + ((size_t)c*NVH + h)*64*128 + (size_t)r*128 + c0;
    #pragma unroll
    for (int i = 0; i < 4; i++)
      *(short8*)&dch[r][c0 + 8*i] = *(const short8*)&drow[8*i];
  }
  if (t < 64) Gs[t] = Gbuf[((size_t)c*NVH + h)*64 + t];
  __syncthreads();

  {
    const int jb = t >> 4, lb = t & 15;
    const int j0 = jb * 4, l0 = lb * 4;
    float acc[4][4] = {};
    for (int dd = 0; dd < 32; dd++) {
      const int d4 = ((dd + lb) & 31) * 4;
      float4 qj[4], kl[4];
      #pragma unroll
      for (int i = 0; i < 4; i++) {
        qj[i] = *(const float4*)&qch[j0 + i][d4];
        kl[i] = *(const float4*)&kch[l0 + i][d4];
      }
      #pragma unroll
      for (int i = 0; i < 4; i++)
        #pragma unroll
        for (int ii = 0; ii < 4; ii++)
          acc[i][ii] += qj[i].x*kl[ii].x + qj[i].y*kl[ii].y
                      + qj[i].z*kl[ii].z + qj[i].w*kl[ii].w;
    }
    #pragma unroll
    for (int i = 0; i < 4; i++)
      #pragma unroll
      for (int ii = 0; ii < 4; ii++) {
        int j = j0 + i, l = l0 + ii;
        PT[l][j] = (l <= j) ? expf(Gs[j] - Gs[l]) * acc[i][ii] : 0.f;
      }
  }
  __syncthreads();

  {
    const int j0 = (t >> 5) * 8;
    const int n0 = (t & 31) * 4;
    float acc2[8][4] = {};
    for (int l = 0; l < 64; l++) {
      float4 p0 = *(const float4*)&PT[l][j0];
      float4 p1 = *(const float4*)&PT[l][j0 + 4];
      float pj[8] = {p0.x,p0.y,p0.z,p0.w,p1.x,p1.y,p1.z,p1.w};
      float dv[4];
      #pragma unroll
      for (int ii = 0; ii < 4; ii++) dv[ii] = __bfloat162float(dch[l][n0 + ii]);
      #pragma unroll
      for (int i = 0; i < 8; i++)
        #pragma unroll
        for (int ii = 0; ii < 4; ii++)
          acc2[i][ii] += pj[i] * dv[ii];
    }
    #pragma unroll
    for (int i = 0; i < 8; i++) {
      float* orow = obuf + ((size_t)(c*64 + j0 + i)*NVH + h)*128 + n0;
      float4 o4 = *(const float4*)orow;
      o4.x += acc2[i][0]; o4.y += acc2[i][1];
      o4.z += acc2[i][2]; o4.w += acc2[i][3];
      *(float4*)orow = o4;
    }
  }
}

// ---------------------------------------------------------------------------
// Gated RMSNorm -> bf16
// ---------------------------------------------------------------------------
__global__ __launch_bounds__(128) void norm_kernel(
    const float* __restrict__ o, const float* __restrict__ gate,
    const float* __restrict__ w_norm, __hip_bfloat16* __restrict__ og) {
  const int s = blockIdx.x, h = blockIdx.y, t = threadIdx.x;
  const size_t idx = (size_t)s * VAL_DIM + h * 128 + t;
  float gt = gate[idx];
  float val = o[idx] * (gt / (1.f + expf(-gt)));
  float ss = val * val;
  #pragma unroll
  for (int off = 1; off < 64; off <<= 1) ss += __shfl_xor(ss, off, 64);
  __shared__ float red[2];
  if ((t & 63) == 0) red[t >> 6] = ss;
  __syncthreads();
  float ms = (red[0] + red[1]) * (1.f / 128.f);
  og[idx] = __float2bfloat16(val * (1.f / sqrtf(ms + 1e-6f)) * w_norm[t]);
}

// ---------------------------------------------------------------------------
extern "C" void kernel_launch(void* const* d_in, const int* in_sizes, int n_in,
                              void* d_out, int out_size, void* d_ws, size_t ws_size,
                              hipStream_t stream) {
  const float* x       = (const float*)d_in[0];
  const float* Wq      = (const float*)d_in[1];
  const float* Wk      = (const float*)d_in[2];
  const float* Wv      = (const float*)d_in[3];
  const float* Wa      = (const float*)d_in[4];
  const float* Wb_     = (const float*)d_in[5];
  const float* Wg      = (const float*)d_in[6];
  const float* Wo      = (const float*)d_in[7];
  const float* conv_q  = (const float*)d_in[8];
  const float* conv_k  = (const float*)d_in[9];
  const float* conv_v  = (const float*)d_in[10];
  const float* A_log   = (const float*)d_in[11];
  const float* dt_bias = (const float*)d_in[12];
  const float* w_norm  = (const float*)d_in[13];
  float* out = (float*)d_out;

  const size_t QK = (size_t)S_LEN * KEY_DIM;   // 4.19M
  const size_t SV = (size_t)S_LEN * VAL_DIM;   // 8.39M
  const size_t SM = (size_t)S_LEN * NVH;       // 65536

  float* W = (float*)d_ws;
  float* q_pre = W;
  float* k_pre = q_pre + QK;
  float* v_pre = k_pre + QK;       // SV floats; later: UbT (bf16) | Db (bf16)
  float* qn    = v_pre + SV;
  float* kn    = qn + QK;
  float* vcb   = kn + QK;          // SV floats; later: obuf
  float* a_pre = vcb + SV;
  float* b_pre = a_pre + SM;
  float* glb   = b_pre + SM;
  float* beta  = glb + SM;
  float* Gbuf  = beta + SM;        // NCH*NVH*64 = 65536
  __hip_bfloat16* xb = (__hip_bfloat16*)(Gbuf + SM);  // 8.39M bf16; later: Wb
  __hip_bfloat16* wb = xb + SV;                       // up to 4.19M bf16

  float* gate = q_pre;             // after convs
  float* obuf = vcb;               // after phase A
  __hip_bfloat16* ogb = (__hip_bfloat16*)kn;  // norm output
  __hip_bfloat16* Wbb = xb;                   // after gate gemm
  __hip_bfloat16* UbT = (__hip_bfloat16*)v_pre;
  __hip_bfloat16* Db  = (__hip_bfloat16*)(v_pre + SV/2);

  const int NC = 256 * 4;
  cast_f2b<<<(S_LEN*HID)/NC, 256, 0, stream>>>(x, xb, S_LEN*HID);

  cast_f2b<<<(KEY_DIM*HID)/NC, 256, 0, stream>>>(Wq, wb, KEY_DIM*HID);
  gemm_bf16_bt<<<dim3(KEY_DIM/128, S_LEN/128), 256, 0, stream>>>(xb, wb, q_pre, S_LEN, KEY_DIM, HID);
  cast_f2b<<<(KEY_DIM*HID)/NC, 256, 0, stream>>>(Wk, wb, KEY_DIM*HID);
  gemm_bf16_bt<<<dim3(KEY_DIM/128, S_LEN/128), 256, 0, stream>>>(xb, wb, k_pre, S_LEN, KEY_DIM, HID);
  cast_f2b<<<(VAL_DIM*HID)/NC, 256, 0, stream>>>(Wv, wb, VAL_DIM*HID);
  gemm_bf16_bt<<<dim3(VAL_DIM/128, S_LEN/128), 256, 0, stream>>>(xb, wb, v_pre, S_LEN, VAL_DIM, HID);
  gemm_bt<<<dim3(1, S_LEN/64), 256, 0, stream>>>(x, Wa, a_pre, S_LEN, NVH, HID);
  gemm_bt<<<dim3(1, S_LEN/64), 256, 0, stream>>>(x, Wb_, b_pre, S_LEN, NVH, HID);

  conv_qk_kernel<<<dim3(S_LEN, NH), 128, 0, stream>>>(q_pre, conv_q, qn, SCALE_Q);
  conv_qk_kernel<<<dim3(S_LEN, NH), 128, 0, stream>>>(k_pre, conv_k, kn, 1.f);
  conv_v_kernel<<<(S_LEN*VAL_DIM)/256, 256, 0, stream>>>(v_pre, conv_v, vcb);
  gb_kernel<<<(S_LEN*NVH)/256, 256, 0, stream>>>(a_pre, b_pre, A_log, dt_bias, glb, beta);

  cast_f2b<<<(VAL_DIM*HID)/NC, 256, 0, stream>>>(Wg, wb, VAL_DIM*HID);
  gemm_bf16_bt<<<dim3(VAL_DIM/128, S_LEN/128), 256, 0, stream>>>(xb, wb, gate, S_LEN, VAL_DIM, HID);

  // chunked delta-rule scan
  phaseA_kernel<<<dim3(NVH, NCH), 256, 0, stream>>>(kn, vcb, glb, beta, Wbb, UbT, Gbuf);
  phaseB_kernel<<<2*NVH, 512, 0, stream>>>(qn, kn, Wbb, UbT, Gbuf, Db, obuf);
  phaseC_kernel<<<dim3(NVH, NCH), 256, 0, stream>>>(qn, kn, Gbuf, Db, obuf);

  norm_kernel<<<dim3(S_LEN, NVH), 128, 0, stream>>>(obuf, gate, w_norm, ogb);

  cast_f2b<<<(HID*VAL_DIM)/NC, 256, 0, stream>>>(Wo, wb, HID*VAL_DIM);
  gemm_bf16_bt<<<dim3(HID/128, S_LEN/128), 256, 0, stream>>>(ogb, wb, out, S_LEN, HID, VAL_DIM);
}

// Round 3
// 1259.605 us; speedup vs baseline: 1.0292x; 1.0073x over previous
//
#include <hip/hip_runtime.h>
#include <hip/hip_bf16.h>
#include <math.h>

#define S_LEN 4096
#define HID   2048
#define NH    8
#define NVH   16
#define DK    128
#define DV    128
#define KEY_DIM  (NH*DK)    // 1024
#define VAL_DIM  (NVH*DV)   // 2048
#define SCALE_Q  0.08838834764831845f  // 128^-0.5
#define CCH 64              // chunk length
#define NCH (S_LEN/CCH)     // 64 chunks

typedef __attribute__((ext_vector_type(8))) short short8;   // 8 bf16
typedef __attribute__((ext_vector_type(4))) float f32x4;

// ---------------------------------------------------------------------------
// float -> bf16 cast
// ---------------------------------------------------------------------------
__global__ __launch_bounds__(256) void cast_f2b(
    const float* __restrict__ in, __hip_bfloat16* __restrict__ out, int n) {
  int i = (blockIdx.x * 256 + threadIdx.x) * 4;
  if (i >= n) return;
  float4 v = *(const float4*)&in[i];
  union { __hip_bfloat16 b[4]; short4 s; } u;
  u.b[0] = __float2bfloat16(v.x); u.b[1] = __float2bfloat16(v.y);
  u.b[2] = __float2bfloat16(v.z); u.b[3] = __float2bfloat16(v.w);
  *(short4*)&out[i] = u.s;
}

// ---------------------------------------------------------------------------
// bf16 MFMA GEMM: C[M,N](fp32) = A[M,K] @ B[N,K]^T  (m97 structure)
// ---------------------------------------------------------------------------
__device__ __forceinline__ void lds_load16(const __hip_bfloat16* g,
                                           __hip_bfloat16* l) {
  __builtin_amdgcn_global_load_lds(
      (const __attribute__((address_space(1))) unsigned int*)g,
      (__attribute__((address_space(3))) unsigned int*)l, 16, 0, 0);
}

__global__ __launch_bounds__(256) void gemm_bf16_bt(
    const __hip_bfloat16* __restrict__ A, const __hip_bfloat16* __restrict__ B,
    float* __restrict__ C, int M, int N, int K) {
  __shared__ __hip_bfloat16 sA[128 * 32];
  __shared__ __hip_bfloat16 sB[128 * 32];
  const int t = threadIdx.x;
  const int wave = t >> 6, lane = t & 63;
  const int bm = blockIdx.y, bn = blockIdx.x;
  const int wm = (wave & 1) * 64, wn = (wave >> 1) * 64;

  f32x4 zero = {0.f, 0.f, 0.f, 0.f};
  f32x4 acc[4][4];
  #pragma unroll
  for (int i = 0; i < 4; i++)
    #pragma unroll
    for (int j = 0; j < 4; j++) acc[i][j] = zero;

  const int r0 = t >> 2,        c0 = (t & 3) * 8;
  const int r1 = (256 + t) >> 2, c1 = ((256 + t) & 3) * 8;
  const __hip_bfloat16* gA0 = A + (size_t)(bm * 128 + r0) * K + c0;
  const __hip_bfloat16* gA1 = A + (size_t)(bm * 128 + r1) * K + c1;
  const __hip_bfloat16* gB0 = B + (size_t)(bn * 128 + r0) * K + c0;
  const __hip_bfloat16* gB1 = B + (size_t)(bn * 128 + r1) * K + c1;
  __hip_bfloat16* lA0 = sA + (size_t)(wave * 64) * 8;
  __hip_bfloat16* lA1 = sA + (size_t)(256 + wave * 64) * 8;
  __hip_bfloat16* lB0 = sB + (size_t)(wave * 64) * 8;
  __hip_bfloat16* lB1 = sB + (size_t)(256 + wave * 64) * 8;

  const int fm = lane & 15, fk = (lane >> 4) * 8;

  for (int k0 = 0; k0 < K; k0 += 32) {
    lds_load16(gA0, lA0); lds_load16(gA1, lA1);
    lds_load16(gB0, lB0); lds_load16(gB1, lB1);
    gA0 += 32; gA1 += 32; gB0 += 32; gB1 += 32;
    __syncthreads();
    short8 a[4], b[4];
    #pragma unroll
    for (int i = 0; i < 4; i++)
      a[i] = *(const short8*)&sA[(size_t)(wm + i * 16 + fm) * 32 + fk];
    #pragma unroll
    for (int j = 0; j < 4; j++)
      b[j] = *(const short8*)&sB[(size_t)(wn + j * 16 + fm) * 32 + fk];
    #pragma unroll
    for (int i = 0; i < 4; i++)
      #pragma unroll
      for (int j = 0; j < 4; j++)
        acc[i][j] = __builtin_amdgcn_mfma_f32_16x16x32_bf16(a[i], b[j], acc[i][j], 0, 0, 0);
    __syncthreads();
  }
  #pragma unroll
  for (int i = 0; i < 4; i++) {
    #pragma unroll
    for (int j = 0; j < 4; j++) {
      int col = bn * 128 + wn + j * 16 + (lane & 15);
      int rw0 = bm * 128 + wm + i * 16 + (lane >> 4) * 4;
      #pragma unroll
      for (int r = 0; r < 4; r++)
        C[(size_t)(rw0 + r) * N + col] = acc[i][j][r];
    }
  }
}

// ---------------------------------------------------------------------------
// fp32 GEMM for the tiny N=16 projections (Wa, Wb)
// ---------------------------------------------------------------------------
__global__ __launch_bounds__(256) void gemm_bt(
    const float* __restrict__ A, const float* __restrict__ B,
    float* __restrict__ C, int M, int N, int K) {
  __shared__ float As[16][68];
  __shared__ float Bs[16][68];
  const int bm = blockIdx.y, bn = blockIdx.x;
  const int t = threadIdx.x;
  const int tx = t & 15, ty = t >> 4;
  const int lrow = t >> 2;
  const int lk0  = (t & 3) * 4;
  const int arow = bm * 64 + lrow;
  const int brow = bn * 64 + lrow;
  const bool bvalid = brow < N;

  float acc[4][4];
  #pragma unroll
  for (int i = 0; i < 4; i++)
    #pragma unroll
    for (int j = 0; j < 4; j++) acc[i][j] = 0.f;

  for (int k0 = 0; k0 < K; k0 += 16) {
    float4 av = *(const float4*)&A[(size_t)arow * K + k0 + lk0];
    float4 bv = bvalid ? *(const float4*)&B[(size_t)brow * K + k0 + lk0]
                       : make_float4(0.f, 0.f, 0.f, 0.f);
    As[lk0+0][lrow] = av.x; As[lk0+1][lrow] = av.y;
    As[lk0+2][lrow] = av.z; As[lk0+3][lrow] = av.w;
    Bs[lk0+0][lrow] = bv.x; Bs[lk0+1][lrow] = bv.y;
    Bs[lk0+2][lrow] = bv.z; Bs[lk0+3][lrow] = bv.w;
    __syncthreads();
    #pragma unroll
    for (int kk = 0; kk < 16; kk++) {
      float4 a = *(const float4*)&As[kk][ty * 4];
      float4 b = *(const float4*)&Bs[kk][tx * 4];
      float ar[4] = {a.x, a.y, a.z, a.w};
      float br[4] = {b.x, b.y, b.z, b.w};
      #pragma unroll
      for (int i = 0; i < 4; i++)
        #pragma unroll
        for (int j = 0; j < 4; j++) acc[i][j] += ar[i] * br[j];
    }
    __syncthreads();
  }
  #pragma unroll
  for (int i = 0; i < 4; i++) {
    int r = bm * 64 + ty * 4 + i;
    #pragma unroll
    for (int j = 0; j < 4; j++) {
      int c = bn * 64 + tx * 4 + j;
      if (c < N) C[(size_t)r * N + c] = acc[i][j];
    }
  }
}

// ---------------------------------------------------------------------------
// conv + SiLU + l2norm for q/k  -> bf16 output (R2: halves q/k traffic for
// phaseA/B/C; the bf16 rounding happened before MFMA anyway)
// ---------------------------------------------------------------------------
__global__ __launch_bounds__(128) void conv_qk_kernel(
    const float* __restrict__ pre, const float* __restrict__ cw,
    __hip_bfloat16* __restrict__ out, float scale) {
  const int s = blockIdx.x, h = blockIdx.y, t = threadIdx.x;
  const int c = h * 128 + t;
  const float4 w = *(const float4*)&cw[c * 4];
  float y = pre[(size_t)s * KEY_DIM + c] * w.w;
  if (s >= 1) y += pre[(size_t)(s-1) * KEY_DIM + c] * w.z;
  if (s >= 2) y += pre[(size_t)(s-2) * KEY_DIM + c] * w.y;
  if (s >= 3) y += pre[(size_t)(s-3) * KEY_DIM + c] * w.x;
  float v = y / (1.f + expf(-y));
  float ss = v * v;
  #pragma unroll
  for (int off = 1; off < 64; off <<= 1) ss += __shfl_xor(ss, off, 64);
  __shared__ float red[2];
  if ((t & 63) == 0) red[t >> 6] = ss;
  __syncthreads();
  float inv = scale / sqrtf(red[0] + red[1] + 1e-6f);
  out[((size_t)s * NH + h) * 128 + t] = __float2bfloat16(v * inv);
}

// ---------------------------------------------------------------------------
// conv + SiLU for v
// ---------------------------------------------------------------------------
__global__ __launch_bounds__(256) void conv_v_kernel(
    const float* __restrict__ pre, const float* __restrict__ cw,
    float* __restrict__ out) {
  const int id = blockIdx.x * 256 + threadIdx.x;
  const int s = id >> 11, c = id & 2047;
  const float4 w = *(const float4*)&cw[c * 4];
  float y = pre[id] * w.w;
  if (s >= 1) y += pre[id - VAL_DIM]     * w.z;
  if (s >= 2) y += pre[id - 2*VAL_DIM]   * w.y;
  if (s >= 3) y += pre[id - 3*VAL_DIM]   * w.x;
  out[id] = y / (1.f + expf(-y));
}

// ---------------------------------------------------------------------------
// gl = -exp(A_log)*softplus(a+dt_bias)  (LOG decay), beta = sigmoid(b)
// ---------------------------------------------------------------------------
__global__ __launch_bounds__(256) void gb_kernel(
    const float* __restrict__ a_pre, const float* __restrict__ b_pre,
    const float* __restrict__ A_log, const float* __restrict__ dt_bias,
    float* __restrict__ gl, float* __restrict__ bv) {
  const int id = blockIdx.x * 256 + threadIdx.x;
  const int h = id & 15;
  float av = a_pre[id] + dt_bias[h];
  float sp = av > 20.f ? av : log1pf(expf(av));
  gl[id] = -expf(A_log[h]) * sp;
  bv[id] = 1.f / (1.f + expf(-b_pre[id]));
}

// ---------------------------------------------------------------------------
// Phase A v3: kn input is now bf16 (convert on load; same f32 compute)
// ---------------------------------------------------------------------------
__global__ __launch_bounds__(256) void phaseA_kernel(
    const __hip_bfloat16* __restrict__ kn, const float* __restrict__ vc,
    const float* __restrict__ gl, const float* __restrict__ bvv,
    __hip_bfloat16* __restrict__ Wb, __hip_bfloat16* __restrict__ UbT,
    float* __restrict__ Gbuf) {
  const int h = blockIdx.x, c = blockIdx.y, sh = h >> 1;
  const int t = threadIdx.x;
  __shared__ float kchT[128][68];   // [dk][j]
  __shared__ float vch[64][132];    // [j][n]
  __shared__ float mm[64][65];
  __shared__ float sol[64][257];    // odd stride: conflict-free per-column
  __shared__ float Gs[64], bet[64], lamB[64];

  {
    const int r = t >> 2, c0 = (t & 3) * 32;
    const __hip_bfloat16* krow = kn + (size_t)(c*64 + r)*KEY_DIM + sh*128 + c0;
    const float* vrow = vc + (size_t)(c*64 + r)*VAL_DIM + h*128 + c0;
    #pragma unroll
    for (int i = 0; i < 4; i++) {
      union { short8 s; __hip_bfloat16 b[8]; } kv;
      kv.s = *(const short8*)&krow[8*i];
      #pragma unroll
      for (int e = 0; e < 8; e++) kchT[c0+8*i+e][r] = __bfloat162float(kv.b[e]);
    }
    #pragma unroll
    for (int i = 0; i < 8; i++)
      *(float4*)&vch[r][c0 + 4*i] = *(const float4*)&vrow[4*i];
  }
  if (t < 64) {
    float g = gl[(size_t)(c*64 + t)*NVH + h];
    #pragma unroll
    for (int off = 1; off < 64; off <<= 1) {
      float p = __shfl_up(g, off, 64);
      if (t >= off) g += p;
    }
    Gs[t] = g;
    float b = bvv[(size_t)(c*64 + t)*NVH + h];
    bet[t] = b;
    lamB[t] = b * expf(g);
    Gbuf[((size_t)c*NVH + h)*64 + t] = g;
  }
  __syncthreads();

  {
    const int j0 = (t >> 4) * 4, l0 = (t & 15) * 4;
    float acc[4][4] = {};
    #pragma unroll 2
    for (int d = 0; d < 128; d++) {
      float4 kj = *(const float4*)&kchT[d][j0];
      float4 kl = *(const float4*)&kchT[d][l0];
      float aj[4] = {kj.x, kj.y, kj.z, kj.w};
      float al[4] = {kl.x, kl.y, kl.z, kl.w};
      #pragma unroll
      for (int i = 0; i < 4; i++)
        #pragma unroll
        for (int ii = 0; ii < 4; ii++)
          acc[i][ii] = fmaf(aj[i], al[ii], acc[i][ii]);
    }
    #pragma unroll
    for (int i = 0; i < 4; i++)
      #pragma unroll
      for (int ii = 0; ii < 4; ii++) {
        int j = j0 + i, l = l0 + ii;
        mm[j][l] = (l < j) ? bet[j] * expf(Gs[j] - Gs[l]) * acc[i][ii] : 0.f;
      }
  }
  __syncthreads();

  {
    const bool isW = t < 128;
    const int col = t & 127;
    for (int j = 0; j < 64; j++) {
      float s0 = isW ? lamB[j] * kchT[col][j] : bet[j] * vch[j][col];
      float s1 = 0.f;
      int l = 0;
      for (; l + 1 < j; l += 2) {
        s0 = fmaf(-mm[j][l],   sol[l][t],   s0);
        s1 = fmaf(-mm[j][l+1], sol[l+1][t], s1);
      }
      if (l < j) s0 = fmaf(-mm[j][l], sol[l][t], s0);
      sol[j][t] = s0 + s1;
    }
  }
  if (t < 128) {
    const size_t base = ((size_t)c*NVH + h) * 64 * 128;
    for (int j = 0; j < 64; j++)
      Wb[base + j*128 + t] = __float2bfloat16(sol[j][t]);
  } else {
    const int n = t - 128;
    const size_t ub = (((size_t)c*NVH + h) * 128 + n) * 64;
    for (int j0 = 0; j0 < 64; j0 += 4) {
      union { unsigned long long u; __hip_bfloat16 b[4]; } p;
      #pragma unroll
      for (int i = 0; i < 4; i++) p.b[i] = __float2bfloat16(sol[j0+i][t]);
      *(unsigned long long*)&UbT[ub + j0] = p.u;
    }
  }
}

// ---------------------------------------------------------------------------
// Phase B v6. R2 post-mortem: 2 waves/SIMD lockstep gave only -5.5% -> the
// bound is per-CU HBM traffic (91.5MB fetch / 32 CUs / 263us = 17GB/s/CU,
// ~45KB per block-chunk = the measured ~9.8k cy/chunk). Attack bytes:
//  - qn/kn are bf16 (halved)
//  - q A-fragments load DIRECTLY global->VGPR (wave-private), double-buffered;
//    q16 LDS buffer + its 8-way-conflict staging writes are gone. The e^G
//    row-scale moves to the epilogue (scale aO rows by e^{G_j} post-MFMA).
//  - XCD-pair remap: (h,vt=0/1) blocks share Wb/q/k; map bid and bid+8 to the
//    same h so the pair lands on the same XCD L2 (round-robin dispatch).
// Same 2 lgkm-only barriers/chunk; k staged bf16 (transpose pack, no cvt).
// ---------------------------------------------------------------------------
__device__ __forceinline__ void bar_lgkm() {
  asm volatile("s_waitcnt lgkmcnt(0)" ::: "memory");
  __builtin_amdgcn_s_barrier();
  asm volatile("" ::: "memory");
}

__global__ __launch_bounds__(512, 2) void phaseB_kernel(
    const __hip_bfloat16* __restrict__ qn, const __hip_bfloat16* __restrict__ kn,
    const __hip_bfloat16* __restrict__ Wb, const __hip_bfloat16* __restrict__ UbT,
    const float* __restrict__ Gbuf,
    __hip_bfloat16* __restrict__ Db, float* __restrict__ obuf) {
  const int bid = blockIdx.x;
  const int h = (bid & 7) | ((bid >> 4) << 3);   // bid, bid+8 -> same h, same XCD
  const int vt = (bid >> 3) & 1;
  const int sh = h >> 1;
  const int t = threadIdx.x, lane = t & 63, w = t >> 6;   // w 0..7
  const int fm = lane & 15, fq = lane >> 4;
  const int jt = w >> 1;          // j-tile (16 rows) for phase-1 / epilogue
  const int nh = w & 1;           // n-half: tj in {2nh, 2nh+1}
  const int dt = w >> 1;          // dk-tile (32 rows) for update/mirror

  __shared__ __hip_bfloat16 S16T[64][136];  // S0 mirror (bf16), [n_loc][dk]
  __shared__ __hip_bfloat16 kT[128][72];    // [dk][j]
  __shared__ __hip_bfloat16 dT[64][72];     // e^{G_C-G_j} Delta, [n_loc][j]
  __shared__ float Gs[64];

  // staging assignments (512 threads): k transpose, 4 dk x 4 j per thread
  const int kj = (t & 15) * 4, kd = (t >> 4) * 4;
  const int j0 = 16*jt + fq*4;                    // epilogue rows

  f32x4 Sacc[2][2];
  #pragma unroll
  for (int ti = 0; ti < 2; ti++)
    #pragma unroll
    for (int i = 0; i < 2; i++) Sacc[ti][i] = (f32x4){0.f,0.f,0.f,0.f};
  for (int i = t; i < 64*136/2; i += 512) ((unsigned int*)S16T)[i] = 0;

  ushort4 krg[4];
  short8 Qnext[4], Qcur[4];
  short8 Wnext[4], Wcur[4];
  unsigned long long Unext[2], Ucur[2];
  float gl64;

  auto prefetch = [&](int c) {
    const int cb = (c*NVH + h) * 64;
    const __hip_bfloat16* qbase = qn + (size_t)(c*64 + 16*jt + fm)*KEY_DIM + sh*128 + fq*8;
    #pragma unroll
    for (int k4 = 0; k4 < 4; k4++)
      Qnext[k4] = *(const short8*)&qbase[k4*32];
    #pragma unroll
    for (int jj = 0; jj < 4; jj++)
      krg[jj] = *(const ushort4*)&kn[(size_t)(c*64 + kj + jj)*KEY_DIM + sh*128 + kd];
    #pragma unroll
    for (int k4 = 0; k4 < 4; k4++)
      Wnext[k4] = *(const short8*)&Wb[(size_t)(cb + 16*jt + fm)*128 + k4*32 + fq*8];
    #pragma unroll
    for (int i = 0; i < 2; i++) {
      const int tj = 2*nh + i;
      Unext[i] = *(const unsigned long long*)
          &UbT[(((size_t)c*NVH + h)*128 + vt*64 + 16*tj + fm)*64 + j0];
    }
    if (t < 64) gl64 = Gbuf[(size_t)cb + t];
  };

  auto stage = [&]() {
    if (t < 64) Gs[t] = gl64;
    union { ushort4 v[4]; unsigned short u[16]; } kk;
    #pragma unroll
    for (int jj = 0; jj < 4; jj++) kk.v[jj] = krg[jj];
    #pragma unroll
    for (int dd = 0; dd < 4; dd++) {
      union { unsigned short u[4]; unsigned long long q; } p;
      #pragma unroll
      for (int jj = 0; jj < 4; jj++) p.u[jj] = kk.u[jj*4 + dd];
      *(unsigned long long*)&kT[kd + dd][kj] = p.q;
    }
  };

  prefetch(0);
  #pragma unroll
  for (int k4 = 0; k4 < 4; k4++) { Qcur[k4] = Qnext[k4]; Wcur[k4] = Wnext[k4]; }
  #pragma unroll
  for (int i = 0; i < 2; i++) Ucur[i] = Unext[i];
  bar_lgkm();               // S16T zero-init visible
  stage();
  bar_lgkm();               // chunk-0 staging + Gs visible

  for (int c = 0; c < NCH; c++) {
    // issue prefetch for c+1 (independent; drains at the reg-copy at chunk end)
    prefetch(c + 1 < NCH ? c + 1 : 0);

    // (1)+(2): X = W S0, opart_raw = q S0   (wave covers j-tile jt x n-half nh)
    f32x4 aX[2], aO[2];
    #pragma unroll
    for (int i = 0; i < 2; i++) {
      aX[i] = (f32x4){0.f,0.f,0.f,0.f};
      aO[i] = (f32x4){0.f,0.f,0.f,0.f};
    }
    __builtin_amdgcn_s_setprio(1);
    #pragma unroll
    for (int k4 = 0; k4 < 4; k4++) {
      #pragma unroll
      for (int i = 0; i < 2; i++) {
        const int tj = 2*nh + i;
        short8 b = *(const short8*)&S16T[16*tj + fm][k4*32 + fq*8];
        aX[i] = __builtin_amdgcn_mfma_f32_16x16x32_bf16(Wcur[k4], b, aX[i], 0, 0, 0);
        aO[i] = __builtin_amdgcn_mfma_f32_16x16x32_bf16(Qcur[k4], b, aO[i], 0, 0, 0);
      }
    }
    __builtin_amdgcn_s_setprio(0);
    // epilogue: Delta, dT, stores. o_intra[j] = e^{G_j} (q_j . S0) -> scale aO.
    const int cb = (c*NVH + h) * 64;
    const float gC = Gs[63];
    float er[4], os[4];
    #pragma unroll
    for (int r2 = 0; r2 < 4; r2++) {
      const float gj = Gs[j0 + r2];
      os[r2] = expf(gj);
      er[r2] = expf(gC - gj);
    }
    #pragma unroll
    for (int i = 0; i < 2; i++) {
      const int tj = 2*nh + i;
      const int n = 16*tj + fm;
      union { unsigned long long u; __hip_bfloat16 b[4]; } u4;
      u4.u = Ucur[i];
      union { __hip_bfloat16 b[4]; unsigned long long u; } pd;
      #pragma unroll
      for (int r2 = 0; r2 < 4; r2++) {
        const int j = j0 + r2;
        float d = __bfloat162float(u4.b[r2]) - aX[i][r2];
        Db[(size_t)(cb + j)*128 + vt*64 + n] = __float2bfloat16(d);
        pd.b[r2] = __float2bfloat16(d * er[r2]);
        obuf[((size_t)(c*64 + j)*NVH + h)*128 + vt*64 + n] = aO[i][r2] * os[r2];
      }
      *(unsigned long long*)&dT[n][j0] = pd.u;
    }
    // decay S
    const float lamC = expf(gC);
    #pragma unroll
    for (int ti = 0; ti < 2; ti++)
      #pragma unroll
      for (int i = 0; i < 2; i++)
        #pragma unroll
        for (int r2 = 0; r2 < 4; r2++) Sacc[ti][i][r2] *= lamC;
    // barrier A: dT visible; all phase-1 S16T reads + epilogue Gs reads done.
    bar_lgkm();
    // (3): S += K^T dT'   (wave covers dk-tile dt x n-half nh)
    __builtin_amdgcn_s_setprio(1);
    #pragma unroll
    for (int ti = 0; ti < 2; ti++) {
      const int m0 = 32*dt + 16*ti;
      #pragma unroll
      for (int kk0 = 0; kk0 < 64; kk0 += 32) {
        short8 aK = *(const short8*)&kT[m0 + fm][kk0 + fq*8];
        #pragma unroll
        for (int i = 0; i < 2; i++) {
          const int tj = 2*nh + i;
          short8 bD = *(const short8*)&dT[16*tj + fm][kk0 + fq*8];
          Sacc[ti][i] = __builtin_amdgcn_mfma_f32_16x16x32_bf16(aK, bD, Sacc[ti][i], 0, 0, 0);
        }
      }
    }
    __builtin_amdgcn_s_setprio(0);
    // refresh bf16 mirror (cols 32dt..32dt+32, rows n in this wave's n-half)
    #pragma unroll
    for (int ti = 0; ti < 2; ti++) {
      const int dk0 = 32*dt + 16*ti + fq*4;
      #pragma unroll
      for (int i = 0; i < 2; i++) {
        const int tj = 2*nh + i;
        const int n = 16*tj + fm;
        union { __hip_bfloat16 b[4]; unsigned long long u; } ps;
        #pragma unroll
        for (int r2 = 0; r2 < 4; r2++) ps.b[r2] = __float2bfloat16(Sacc[ti][i][r2]);
        *(unsigned long long*)&S16T[n][dk0] = ps.u;
      }
    }
    // stage c+1 k -> LDS; pull prefetched regs into cur
    stage();
    #pragma unroll
    for (int k4 = 0; k4 < 4; k4++) { Qcur[k4] = Qnext[k4]; Wcur[k4] = Wnext[k4]; }
    #pragma unroll
    for (int i = 0; i < 2; i++) Ucur[i] = Unext[i];
    // barrier B: S16T mirror + Gs + kT staging visible for chunk c+1
    bar_lgkm();
  }
}

// ---------------------------------------------------------------------------
// Phase C v2: qn/kn are bf16 (convert on load; same f32 compute)
// ---------------------------------------------------------------------------
__global__ __launch_bounds__(256) void phaseC_kernel(
    const __hip_bfloat16* __restrict__ qn, const __hip_bfloat16* __restrict__ kn,
    const float* __restrict__ Gbuf, const __hip_bfloat16* __restrict__ Db,
    float* __restrict__ obuf) {
  const int h = blockIdx.x, c = blockIdx.y, sh = h >> 1;
  const int t = threadIdx.x;
  __shared__ float qch[64][132];
  __shared__ float kch[64][132];
  __shared__ float PT[64][68];              // [l][j]
  __shared__ __hip_bfloat16 dch[64][136];   // [l][n]
  __shared__ float Gs[64];

  {
    const int r = t >> 2, c0 = (t & 3) * 32;
    const __hip_bfloat16* qrow = qn + (size_t)(c*64 + r)*KEY_DIM + sh*128 + c0;
    const __hip_bfloat16* krow = kn + (size_t)(c*64 + r)*KEY_DIM + sh*128 + c0;
    #pragma unroll
    for (int i = 0; i < 4; i++) {
      union { short8 s; __hip_bfloat16 b[8]; } qv, kv;
      qv.s = *(const short8*)&qrow[8*i];
      kv.s = *(const short8*)&krow[8*i];
      #pragma unroll
      for (int e = 0; e < 8; e++) {
        qch[r][c0 + 8*i + e] = __bfloat162float(qv.b[e]);
        kch[r][c0 + 8*i + e] = __bfloat162float(kv.b[e]);
      }
    }
    const __hip_bfloat16* drow = Db + ((size_t)c*NVH + h)*64*128 + (size_t)r*128 + c0;
    #pragma unroll
    for (int i = 0; i < 4; i++)
      *(short8*)&dch[r][c0 + 8*i] = *(const short8*)&drow[8*i];
  }
  if (t < 64) Gs[t] = Gbuf[((size_t)c*NVH + h)*64 + t];
  __syncthreads();

  {
    const int jb = t >> 4, lb = t & 15;
    const int j0 = jb * 4, l0 = lb * 4;
    float acc[4][4] = {};
    for (int dd = 0; dd < 32; dd++) {
      const int d4 = ((dd + lb) & 31) * 4;
      float4 qj[4], kl[4];
      #pragma unroll
      for (int i = 0; i < 4; i++) {
        qj[i] = *(const float4*)&qch[j0 + i][d4];
        kl[i] = *(const float4*)&kch[l0 + i][d4];
      }
      #pragma unroll
      for (int i = 0; i < 4; i++)
        #pragma unroll
        for (int ii = 0; ii < 4; ii++)
          acc[i][ii] += qj[i].x*kl[ii].x + qj[i].y*kl[ii].y
                      + qj[i].z*kl[ii].z + qj[i].w*kl[ii].w;
    }
    #pragma unroll
    for (int i = 0; i < 4; i++)
      #pragma unroll
      for (int ii = 0; ii < 4; ii++) {
        int j = j0 + i, l = l0 + ii;
        PT[l][j] = (l <= j) ? expf(Gs[j] - Gs[l]) * acc[i][ii] : 0.f;
      }
  }
  __syncthreads();

  {
    const int j0 = (t >> 5) * 8;
    const int n0 = (t & 31) * 4;
    float acc2[8][4] = {};
    for (int l = 0; l < 64; l++) {
      float4 p0 = *(const float4*)&PT[l][j0];
      float4 p1 = *(const float4*)&PT[l][j0 + 4];
      float pj[8] = {p0.x,p0.y,p0.z,p0.w,p1.x,p1.y,p1.z,p1.w};
      float dv[4];
      #pragma unroll
      for (int ii = 0; ii < 4; ii++) dv[ii] = __bfloat162float(dch[l][n0 + ii]);
      #pragma unroll
      for (int i = 0; i < 8; i++)
        #pragma unroll
        for (int ii = 0; ii < 4; ii++)
          acc2[i][ii] += pj[i] * dv[ii];
    }
    #pragma unroll
    for (int i = 0; i < 8; i++) {
      float* orow = obuf + ((size_t)(c*64 + j0 + i)*NVH + h)*128 + n0;
      float4 o4 = *(const float4*)orow;
      o4.x += acc2[i][0]; o4.y += acc2[i][1];
      o4.z += acc2[i][2]; o4.w += acc2[i][3];
      *(float4*)orow = o4;
    }
  }
}

// ---------------------------------------------------------------------------
// Gated RMSNorm -> bf16
// ---------------------------------------------------------------------------
__global__ __launch_bounds__(128) void norm_kernel(
    const float* __restrict__ o, const float* __restrict__ gate,
    const float* __restrict__ w_norm, __hip_bfloat16* __restrict__ og) {
  const int s = blockIdx.x, h = blockIdx.y, t = threadIdx.x;
  const size_t idx = (size_t)s * VAL_DIM + h * 128 + t;
  float gt = gate[idx];
  float val = o[idx] * (gt / (1.f + expf(-gt)));
  float ss = val * val;
  #pragma unroll
  for (int off = 1; off < 64; off <<= 1) ss += __shfl_xor(ss, off, 64);
  __shared__ float red[2];
  if ((t & 63) == 0) red[t >> 6] = ss;
  __syncthreads();
  float ms = (red[0] + red[1]) * (1.f / 128.f);
  og[idx] = __float2bfloat16(val * (1.f / sqrtf(ms + 1e-6f)) * w_norm[t]);
}

// ---------------------------------------------------------------------------
extern "C" void kernel_launch(void* const* d_in, const int* in_sizes, int n_in,
                              void* d_out, int out_size, void* d_ws, size_t ws_size,
                              hipStream_t stream) {
  const float* x       = (const float*)d_in[0];
  const float* Wq      = (const float*)d_in[1];
  const float* Wk      = (const float*)d_in[2];
  const float* Wv      = (const float*)d_in[3];
  const float* Wa      = (const float*)d_in[4];
  const float* Wb_     = (const float*)d_in[5];
  const float* Wg      = (const float*)d_in[6];
  const float* Wo      = (const float*)d_in[7];
  const float* conv_q  = (const float*)d_in[8];
  const float* conv_k  = (const float*)d_in[9];
  const float* conv_v  = (const float*)d_in[10];
  const float* A_log   = (const float*)d_in[11];
  const float* dt_bias = (const float*)d_in[12];
  const float* w_norm  = (const float*)d_in[13];
  float* out = (float*)d_out;

  const size_t QK = (size_t)S_LEN * KEY_DIM;   // 4.19M
  const size_t SV = (size_t)S_LEN * VAL_DIM;   // 8.39M
  const size_t SM = (size_t)S_LEN * NVH;       // 65536

  float* W = (float*)d_ws;
  float* q_pre = W;
  float* k_pre = q_pre + QK;
  float* v_pre = k_pre + QK;       // SV floats; later: UbT (bf16) | Db (bf16)
  float* qn    = v_pre + SV;       // bf16 now (slot kept float-sized)
  float* kn    = qn + QK;          // bf16 now; later: ogb
  float* vcb   = kn + QK;          // SV floats; later: obuf
  float* a_pre = vcb + SV;
  float* b_pre = a_pre + SM;
  float* glb   = b_pre + SM;
  float* beta  = glb + SM;
  float* Gbuf  = beta + SM;        // NCH*NVH*64 = 65536
  __hip_bfloat16* xb = (__hip_bfloat16*)(Gbuf + SM);  // 8.39M bf16; later: Wb
  __hip_bfloat16* wb = xb + SV;                       // up to 4.19M bf16

  float* gate = q_pre;             // after convs
  float* obuf = vcb;               // after phase A
  __hip_bfloat16* qnb = (__hip_bfloat16*)qn;
  __hip_bfloat16* knb = (__hip_bfloat16*)kn;
  __hip_bfloat16* ogb = (__hip_bfloat16*)kn;  // norm output (after phaseC)
  __hip_bfloat16* Wbb = xb;                   // after gate gemm
  __hip_bfloat16* UbT = (__hip_bfloat16*)v_pre;
  __hip_bfloat16* Db  = (__hip_bfloat16*)(v_pre + SV/2);

  const int NC = 256 * 4;
  cast_f2b<<<(S_LEN*HID)/NC, 256, 0, stream>>>(x, xb, S_LEN*HID);

  cast_f2b<<<(KEY_DIM*HID)/NC, 256, 0, stream>>>(Wq, wb, KEY_DIM*HID);
  gemm_bf16_bt<<<dim3(KEY_DIM/128, S_LEN/128), 256, 0, stream>>>(xb, wb, q_pre, S_LEN, KEY_DIM, HID);
  cast_f2b<<<(KEY_DIM*HID)/NC, 256, 0, stream>>>(Wk, wb, KEY_DIM*HID);
  gemm_bf16_bt<<<dim3(KEY_DIM/128, S_LEN/128), 256, 0, stream>>>(xb, wb, k_pre, S_LEN, KEY_DIM, HID);
  cast_f2b<<<(VAL_DIM*HID)/NC, 256, 0, stream>>>(Wv, wb, VAL_DIM*HID);
  gemm_bf16_bt<<<dim3(VAL_DIM/128, S_LEN/128), 256, 0, stream>>>(xb, wb, v_pre, S_LEN, VAL_DIM, HID);
  gemm_bt<<<dim3(1, S_LEN/64), 256, 0, stream>>>(x, Wa, a_pre, S_LEN, NVH, HID);
  gemm_bt<<<dim3(1, S_LEN/64), 256, 0, stream>>>(x, Wb_, b_pre, S_LEN, NVH, HID);

  conv_qk_kernel<<<dim3(S_LEN, NH), 128, 0, stream>>>(q_pre, conv_q, qnb, SCALE_Q);
  conv_qk_kernel<<<dim3(S_LEN, NH), 128, 0, stream>>>(k_pre, conv_k, knb, 1.f);
  conv_v_kernel<<<(S_LEN*VAL_DIM)/256, 256, 0, stream>>>(v_pre, conv_v, vcb);
  gb_kernel<<<(S_LEN*NVH)/256, 256, 0, stream>>>(a_pre, b_pre, A_log, dt_bias, glb, beta);

  cast_f2b<<<(VAL_DIM*HID)/NC, 256, 0, stream>>>(Wg, wb, VAL_DIM*HID);
  gemm_bf16_bt<<<dim3(VAL_DIM/128, S_LEN/128), 256, 0, stream>>>(xb, wb, gate, S_LEN, VAL_DIM, HID);

  // chunked delta-rule scan
  phaseA_kernel<<<dim3(NVH, NCH), 256, 0, stream>>>(knb, vcb, glb, beta, Wbb, UbT, Gbuf);
  phaseB_kernel<<<2*NVH, 512, 0, stream>>>(qnb, knb, Wbb, UbT, Gbuf, Db, obuf);
  phaseC_kernel<<<dim3(NVH, NCH), 256, 0, stream>>>(qnb, knb, Gbuf, Db, obuf);

  norm_kernel<<<dim3(S_LEN, NVH), 128, 0, stream>>>(obuf, gate, w_norm, ogb);

  cast_f2b<<<(HID*VAL_DIM)/NC, 256, 0, stream>>>(Wo, wb, HID*VAL_DIM);
  gemm_bf16_bt<<<dim3(HID/128, S_LEN/128), 256, 0, stream>>>(ogb, wb, out, S_LEN, HID, VAL_DIM);
}